// Round 9
// baseline (198.393 us; speedup 1.0000x reference)
//
#include <hip/hip_runtime.h>
#include <cstdint>
#include <cstddef>

#define N_PIX   16384
#define K_EMB   8192
#define DDIM    256

// ws layout (bytes)
#define WS_A8       0           // A fp8 chunk-major [128][8][4096]   4194304
#define WS_E8       4194304     // E fp8 (x8192) [64][8][4096]        2097152
#define WS_KEYS     6291456     // keys [32 subs][16384] uint2        4194304
#define WS_ZSQ      23068672    // 16384*4
#define WS_ESQ      23134208    // 8192*4
#define WS_LOSS     23166976    // 8
#define WS_CNT      23166984    // 4

typedef float f32x4 __attribute__((ext_vector_type(4)));

__device__ __forceinline__ unsigned int f32_sortable(float f) {
    unsigned int u = __float_as_uint(f);
    return (u & 0x80000000u) ? ~u : (u | 0x80000000u);
}

// fp32 -> OCP e4m3fn RNE (fallback path; handles subnormals)
__device__ __forceinline__ unsigned char f2fp8(float x) {
    unsigned ub = __float_as_uint(x);
    unsigned sgn = (ub >> 24) & 0x80u;
    unsigned b = ub & 0x7FFFFFFFu;
    unsigned out;
    if (__uint_as_float(b) < 0.015625f) {
        out = (unsigned)(int)rintf(__uint_as_float(b) * 512.0f);
    } else {
        unsigned r = b + 0x7FFFFu + ((b >> 20) & 1u);
        int er = (int)(r >> 23) - 127;
        out = (unsigned)(((er + 7) << 3) | ((r >> 20) & 7u));
    }
    return (unsigned char)(out | sgn);
}

#if defined(__has_builtin)
#if __has_builtin(__builtin_amdgcn_cvt_pk_fp8_f32)
#define HAVE_CVT_FP8 1
#endif
#endif

__device__ __forceinline__ unsigned pack4_fp8(float a, float b, float c, float d) {
#ifdef HAVE_CVT_FP8
    int pk = 0;
    pk = __builtin_amdgcn_cvt_pk_fp8_f32(a, b, pk, false);
    pk = __builtin_amdgcn_cvt_pk_fp8_f32(c, d, pk, true);
    return (unsigned)pk;
#else
    return (unsigned)f2fp8(a) | ((unsigned)f2fp8(b) << 8)
         | ((unsigned)f2fp8(c) << 16) | ((unsigned)f2fp8(d) << 24);
#endif
}

__device__ __forceinline__ void async16(const unsigned char* g, unsigned char* l) {
    __builtin_amdgcn_global_load_lds(
        (const __attribute__((address_space(1))) void*)g,
        (__attribute__((address_space(3))) void*)l, 16, 0, 0);
}

// np pairwise-sum of squares over 256 contiguous LDS floats (one thread)
__device__ __forceinline__ float np_pairwise_sq256(const float* row) {
    float r[16];
#pragma unroll
    for (int j = 0; j < 16; ++j) r[j] = 0.f;
#pragma unroll
    for (int c = 0; c < 256; ++c) {
        float x  = row[c];
        float sq = __fmul_rn(x, x);
        int slot = ((c >> 7) << 3) | (c & 7);
        r[slot] = __fadd_rn(r[slot], sq);
    }
    float h0 = __fadd_rn(
        __fadd_rn(__fadd_rn(r[0], r[1]), __fadd_rn(r[2], r[3])),
        __fadd_rn(__fadd_rn(r[4], r[5]), __fadd_rn(r[6], r[7])));
    float h1 = __fadd_rn(
        __fadd_rn(__fadd_rn(r[8], r[9]), __fadd_rn(r[10], r[11])),
        __fadd_rn(__fadd_rn(r[12], r[13]), __fadd_rn(r[14], r[15])));
    return __fadd_rn(h0, h1);
}

// chunk-major byte offset for (row-in-128 r, byte-column c) within one
// 32 KB block: ks = c>>5, h = (c>>4)&1, s = h ^ ((r>>2)&1)
__device__ __forceinline__ size_t cm_addr(int r, int c) {
    int ks = c >> 5;
    int h  = (c >> 4) & 1;
    int s  = h ^ ((r >> 2) & 1);
    return (size_t)ks * 4096 + (size_t)r * 32 + s * 16 + (c & 15);
}

// ---------------------------------------------------------------- kernel 1
// unchanged from R4
__global__ __launch_bounds__(256) void prep_kernel(
        const float* __restrict__ z, const float* __restrict__ emb,
        unsigned char* __restrict__ Af8, unsigned char* __restrict__ Ef8,
        float* __restrict__ zsq, float* __restrict__ esq,
        double* __restrict__ lossAcc, unsigned* __restrict__ doneCnt) {
    __shared__ float tile[32][257];
    int blk = blockIdx.x;
    int t   = threadIdx.x;
    if (blk < 512) {
        int b   = blk >> 5;
        int hw0 = (blk & 31) * 32;
        const float* zb = z + (size_t)b * 262144 + hw0;
        int c0  = t >> 3;
        int px4 = t & 7;
#pragma unroll
        for (int cc = 0; cc < 8; ++cc) {
            int c = cc * 32 + c0;
            float4 v = *(const float4*)&zb[(size_t)c * 1024 + px4 * 4];
            tile[px4 * 4 + 0][c] = v.x;
            tile[px4 * 4 + 1][c] = v.y;
            tile[px4 * 4 + 2][c] = v.z;
            tile[px4 * 4 + 3][c] = v.w;
        }
        __syncthreads();
        int p0 = b * 1024 + hw0;
        int wv = t >> 6, lane = t & 63;
#pragma unroll
        for (int iter = 0; iter < 8; ++iter) {
            int pl = iter * 4 + wv;
            unsigned pk = pack4_fp8(tile[pl][lane * 4 + 0], tile[pl][lane * 4 + 1],
                                    tile[pl][lane * 4 + 2], tile[pl][lane * 4 + 3]);
            int p  = p0 + pl;
            int mb = p >> 7, r = p & 127;
            *(unsigned*)(Af8 + (size_t)mb * 32768 + cm_addr(r, lane * 4)) = pk;
        }
        if (t < 32) zsq[p0 + t] = np_pairwise_sq256(tile[t]);
        if (blk == 0 && t == 0) { *lossAcc = 0.0; *doneCnt = 0u; }
    } else {
        int k0 = (blk - 512) * 32;
        const float4* eg = (const float4*)(emb + (size_t)k0 * DDIM);
#pragma unroll
        for (int i = 0; i < 8; ++i) {
            int idx = i * 256 + t;
            int row = idx >> 6, c4 = idx & 63;
            float4 v = eg[idx];
            *(float4*)&tile[row][c4 * 4] = v;
        }
        __syncthreads();
#pragma unroll
        for (int i = 0; i < 8; ++i) {
            int idx = i * 256 + t;
            int row = idx >> 6, c4 = idx & 63;
            const float* rp = &tile[row][c4 * 4];
            int kg = k0 + row;
            int nb = kg >> 7, rr = kg & 127;
            *(unsigned*)(Ef8 + (size_t)nb * 32768 + cm_addr(rr, c4 * 4)) =
                pack4_fp8(rp[0] * 8192.0f, rp[1] * 8192.0f,
                          rp[2] * 8192.0f, rp[3] * 8192.0f);
        }
        if (t < 32) esq[k0 + t] = np_pairwise_sq256(tile[t]);
    }
}

// winner float (idx in low 13 mantissa bits) -> integer key
__device__ __forceinline__ unsigned pack_key(float w) {
    float uf = __builtin_fmaf(w, -512.0f, 262144.0f);
    uf = fminf(uf, 524287.0f);
    unsigned u = (unsigned)uf;
    return (u << 13) | (__float_as_uint(w) & 0x1FFFu);
}

// ---------------------------------------------------------------- kernel 2
// R9: T3 software pipeline. Double-buffered Bs[2]; the 8 next-tile
// async16 chunks are issued INTERLEAVED with the current tile's 8 ks
// MFMA steps (issue-early), so the old serial stage window between the
// two barriers disappears. ONE barrier per j: the compiler's
// vmcnt(0)-before-s_barrier drains loads issued ~2000 cyc earlier (cheap).
// A-fragments register-resident (R6). Occupancy is known-irrelevant
// (R1/R6), so LDS 64KB+dbuf is fine.
__global__ __launch_bounds__(256) void mfma_score_kernel(
        const unsigned char* __restrict__ Af8,
        const unsigned char* __restrict__ Ef8,
        unsigned int* __restrict__ keys) {
    union SM {
        unsigned char Bs[2][8][4096];    // 64 KB: E tiles, double-buffered
        struct { uint2 ep[128][33]; } e; // 33.8 KB, reused in epilogue
    };
    __shared__ SM sm;

    const int g  = blockIdx.x;      // 0..15
    const int mb = blockIdx.y;      // 0..127
    const int t = threadIdx.x;
    const int w = t >> 6, lane = t & 63;
    const int wm = w >> 1, wn = w & 1;
    const int quad = lane >> 4, l16 = lane & 15;

    // stage first E tile into Bs[0]
    {
        const unsigned char* Eg = Ef8 + (size_t)(g * 4) * 32768 + t * 16;
#pragma unroll
        for (int ks = 0; ks < 8; ++ks)
            async16(Eg + ks * 4096, &sm.Bs[0][ks][t * 16]);
    }

    int aaddr[4], baddr[4];
#pragma unroll
    for (int fi = 0; fi < 4; ++fi) {
        int row = wm * 64 + fi * 16 + l16;
        int gg  = (quad >> 1) ^ ((row >> 2) & 1);
        aaddr[fi] = row * 32 + gg * 16 + (quad & 1) * 8;
    }
#pragma unroll
    for (int fj = 0; fj < 4; ++fj) {
        int row = wn * 64 + fj * 16 + l16;
        int gg  = (quad >> 1) ^ ((row >> 2) & 1);
        baddr[fj] = row * 32 + gg * 16 + (quad & 1) * 8;
    }

    // A-fragments: one-time direct L2->reg load (R6; outside inner loop)
    long long afr[4][8];
    {
        const unsigned char* Agb = Af8 + (size_t)mb * 32768;
#pragma unroll
        for (int fi = 0; fi < 4; ++fi)
#pragma unroll
            for (int ks = 0; ks < 8; ++ks)
                afr[fi][ks] = *(const long long*)(Agb + ks * 4096 + aaddr[fi]);
    }

    const float NEGINF = __int_as_float(0xFF800000);
    float t2a[16], t2b[16];
#pragma unroll
    for (int i = 0; i < 16; ++i) { t2a[i] = NEGINF; t2b[i] = NEGINF; }

    __syncthreads();   // E0 staged (vmcnt(0) drain at barrier)

#pragma unroll 1
    for (int j = 0; j < 4; ++j) {
        const int cur = j & 1, nxt = cur ^ 1;
        const unsigned char* Egn =
            Ef8 + (size_t)(g * 4 + j + 1) * 32768 + t * 16;

        f32x4 acc[4][4];
#pragma unroll
        for (int i = 0; i < 4; ++i)
#pragma unroll
            for (int jj = 0; jj < 4; ++jj)
#pragma unroll
                for (int r = 0; r < 4; ++r) acc[i][jj][r] = 0.f;

#pragma unroll
        for (int ks = 0; ks < 8; ++ks) {
            // issue next-tile chunk ks early — hides under this ks's MFMAs
            if (j < 3)
                async16(Egn + ks * 4096, &sm.Bs[nxt][ks][t * 16]);
            long long bfr[4];
#pragma unroll
            for (int fj = 0; fj < 4; ++fj)
                bfr[fj] = *(const long long*)&sm.Bs[cur][ks][baddr[fj]];
            __builtin_amdgcn_s_setprio(1);
#pragma unroll
            for (int fi = 0; fi < 4; ++fi)
#pragma unroll
                for (int fj = 0; fj < 4; ++fj)
                    acc[fi][fj] = __builtin_amdgcn_mfma_f32_16x16x32_fp8_fp8(
                        afr[fi][ks], bfr[fj], acc[fi][fj], 0, 0, 0);
            __builtin_amdgcn_s_setprio(0);
        }

        // selection (pure VALU; staged loads still in flight)
        const int nb = g * 4 + j;
        const unsigned idx0 = (unsigned)(nb * 128 + wn * 64 + l16);
#pragma unroll
        for (int fi = 0; fi < 4; ++fi) {
#pragma unroll
            for (int r = 0; r < 4; ++r) {
                const int ai = fi * 4 + r;
                float a0 = t2a[ai], b0 = t2b[ai];
#pragma unroll
                for (int fj = 0; fj < 4; ++fj) {
                    float v = acc[fi][fj][r];
                    float wv = __uint_as_float(
                        (__float_as_uint(v) & 0xFFFFE000u) | (idx0 + fj * 16));
                    float mn = fminf(a0, wv);
                    a0 = fmaxf(a0, wv);
                    b0 = fmaxf(b0, mn);
                }
                t2a[ai] = a0; t2b[ai] = b0;
            }
        }
        __syncthreads();   // drains own loads (issued early), syncs buffers
    }

    // epilogue: winners -> integer keys -> LDS -> per-(row,half) reduce
#pragma unroll
    for (int fi = 0; fi < 4; ++fi) {
#pragma unroll
        for (int r = 0; r < 4; ++r) {
            const int ai = fi * 4 + r;
            int row = wm * 64 + fi * 16 + quad * 4 + r;
            sm.e.ep[row][wn * 16 + l16] =
                make_uint2(pack_key(t2a[ai]), pack_key(t2b[ai]));
        }
    }
    __syncthreads();

    {
        int row = t >> 1, half = t & 1, h0 = half * 16;
        uint2 mv = sm.e.ep[row][h0];
#pragma unroll
        for (int i = 1; i < 16; ++i) {
            uint2 av = sm.e.ep[row][h0 + i];
            unsigned n0 = min(mv.x, av.x);
            unsigned n1 = min(max(mv.x, av.x), min(mv.y, av.y));
            mv.x = n0; mv.y = n1;
        }
        ((uint2*)keys)[(size_t)(g * 2 + half) * N_PIX + (mb * 128 + row)] = mv;
    }
}

// ---------------------------------------------------------------- kernel 3
// unchanged from R4 (parallel rescore)
__global__ __launch_bounds__(256) void final_kernel(
        const unsigned int* __restrict__ keys,
        const float* __restrict__ z, const float* __restrict__ emb,
        const float* __restrict__ zsq, const float* __restrict__ esq,
        float* __restrict__ out, float* __restrict__ idx_out,
        float* __restrict__ loss_out,
        double* __restrict__ lossAcc, unsigned* __restrict__ doneCnt) {
    __shared__ float ztile[16][260];
    __shared__ uint2 kt[16][33];
    __shared__ int   scand[16][64];
    __shared__ unsigned long long ckey[1024];
    __shared__ int   soff[17];
    __shared__ int   scnt[16];
    __shared__ int   pxmap[1024];
    __shared__ float szs[16];
    __shared__ int   sidx[16];

    int blk = blockIdx.x;                // 0..1023 = b*64 + hh
    int b = blk >> 6, hh = blk & 63;
    int t = threadIdx.x;
    int p0 = b * 1024 + hh * 16;
    const float* zb = z + (size_t)b * 262144 + hh * 16;
    {
        int px = t & 15, cb = t >> 4;
#pragma unroll
        for (int cc = 0; cc < 16; ++cc) {
            int c = cc * 16 + cb;
            ztile[px][c] = zb[(size_t)c * 1024 + px];
        }
    }
    {
        const uint2* kg = (const uint2*)keys;
#pragma unroll
        for (int itr = 0; itr < 2; ++itr) {
            int idx = itr * 256 + t;
            int px = idx & 15, hf = idx >> 4;
            kt[px][hf] = kg[(size_t)hf * N_PIX + p0 + px];
        }
    }
    if (t < 16) szs[t] = zsq[p0 + t];
    __syncthreads();

    // ---- Phase A: threshold + compact candidate lists
    {
        int wq = t >> 6, lane = t & 63;
#pragma unroll 1
        for (int i = 0; i < 4; ++i) {
            int px = wq * 4 + i;
            uint2 ka = (lane < 32) ? kt[px][lane] : make_uint2(~0u, ~0u);
            unsigned m = min(ka.x, ka.y);
#pragma unroll
            for (int off = 32; off >= 1; off >>= 1)
                m = min(m, (unsigned)__shfl_xor((int)m, off, 64));
            unsigned thr = (m >> 13) + 1600;   // margin 1600*2^-21 = 7.6e-4

            bool h0 = (lane < 32) && ((ka.x >> 13) <= thr);
            bool h1 = (lane < 32) && ((ka.y >> 13) <= thr);
            unsigned long long m0 = __ballot(h0);
            unsigned long long m1 = __ballot(h1);
            int c0 = __popcll(m0);
            unsigned long long below = (lane == 63) ? ~0ull >> 1
                                     : ((1ull << lane) - 1);
            if (h0) scand[px][__popcll(m0 & below)] = (int)(ka.x & 0x1FFFu);
            if (h1) scand[px][c0 + __popcll(m1 & below)] = (int)(ka.y & 0x1FFFu);
            if (lane == 0) scnt[px] = c0 + __popcll(m1);
        }
    }
    __syncthreads();

    // ---- scan counts -> soff (wave 0), then pxmap
    if (t < 64) {
        int v = (t < 16) ? scnt[t] : 0;
#pragma unroll
        for (int o = 1; o < 16; o <<= 1) {
            int u = __shfl_up(v, o, 64);
            if (t >= o) v += u;
        }
        if (t < 16) soff[t + 1] = v;
        if (t == 0) soff[0] = 0;
    }
    __syncthreads();
    int total = soff[16];
    for (int f = t; f < total; f += 256) {
        int lo = 0, hi = 15;
        while (lo < hi) {
            int mid = (lo + hi + 1) >> 1;
            if (soff[mid] <= f) lo = mid; else hi = mid - 1;
        }
        pxmap[f] = lo;
    }
    __syncthreads();

    // ---- Phase B: parallel rescore, one candidate per 16-lane group
    {
        int gid = t >> 4, l16 = t & 15;
        const float4* emb4 = (const float4*)emb;
#pragma unroll 1
        for (int f = gid; f < total; f += 16) {
            int px = pxmap[f];
            int k  = scand[px][f - soff[px]];
            double d = 0.0;
#pragma unroll
            for (int q = 0; q < 4; ++q) {
                float4 ev = emb4[(size_t)k * 64 + q * 16 + l16];
                const float* zp = &ztile[px][(q * 16 + l16) * 4];
                d += (double)zp[0] * ev.x + (double)zp[1] * ev.y
                   + (double)zp[2] * ev.z + (double)zp[3] * ev.w;
            }
#pragma unroll
            for (int o = 1; o < 16; o <<= 1) d += __shfl_xor(d, o, 64);
            if (l16 == 0) {
                float df = (float)d;
                float s  = __fsub_rn(__fadd_rn(szs[px], esq[k]),
                                     __fmul_rn(2.0f, df));
                ckey[f] = ((unsigned long long)f32_sortable(s) << 32)
                        | (unsigned)k;
            }
        }
    }
    __syncthreads();

    // ---- Phase C: per-pixel u64 min (16 threads each)
    {
        int cpx = t >> 4, ci = t & 15;
        unsigned long long best = ~0ull;
        for (int f = soff[cpx] + ci; f < soff[cpx + 1]; f += 16) {
            unsigned long long v = ckey[f];
            best = v < best ? v : best;
        }
#pragma unroll
        for (int o = 1; o < 16; o <<= 1) {
            unsigned long long ov =
                (unsigned long long)__shfl_xor((long long)best, o, 64);
            best = ov < best ? ov : best;
        }
        if (ci == 0) {
            int k = (int)(unsigned)(best & 0xffffffffu);
            sidx[cpx] = k;
            idx_out[p0 + cpx] = (float)k;
        }
    }
    __syncthreads();

    // ---- gather + loss (unchanged)
    int px2 = t & 15, cy = t >> 4;
    int kk = sidx[px2];
    const float* er = emb + (size_t)kk * DDIM;
    float* ob = out + (size_t)b * 262144 + hh * 16;
    float local = 0.f;
#pragma unroll 4
    for (int it = 0; it < 16; ++it) {
        int c = it * 16 + cy;
        float q = er[c];
        float d = q - ztile[px2][c];
        ob[(size_t)c * 1024 + px2] = q;
        local += d * d;
    }
#pragma unroll
    for (int off = 32; off >= 1; off >>= 1) local += __shfl_down(local, off, 64);
    __shared__ float wsum[4];
    if ((t & 63) == 0) wsum[t >> 6] = local;
    __syncthreads();
    if (t == 0) {
        double s = (double)wsum[0] + (double)wsum[1]
                 + (double)wsum[2] + (double)wsum[3];
        atomicAdd(lossAcc, s);
        __threadfence();
        unsigned old = atomicAdd(doneCnt, 1u);
        if (old == 1023u) {
            double tot = atomicAdd(lossAcc, 0.0);
            *loss_out = (float)(tot * (1.25 / 4194304.0));
        }
    }
}

// ----------------------------------------------------------------
extern "C" void kernel_launch(void* const* d_in, const int* in_sizes, int n_in,
                              void* d_out, int out_size, void* d_ws, size_t ws_size,
                              hipStream_t stream) {
    const float* z   = (const float*)d_in[0];
    const float* emb = (const float*)d_in[1];
    float* out = (float*)d_out;
    char* ws = (char*)d_ws;

    unsigned char* Af8 = (unsigned char*)(ws + WS_A8);
    unsigned char* Ef8 = (unsigned char*)(ws + WS_E8);
    unsigned int* keys = (unsigned int*)(ws + WS_KEYS);
    float* zsq      = (float*)(ws + WS_ZSQ);
    float* esq      = (float*)(ws + WS_ESQ);
    double* lossAcc = (double*)(ws + WS_LOSS);
    unsigned* doneCnt = (unsigned*)(ws + WS_CNT);

    prep_kernel<<<768, 256, 0, stream>>>(z, emb, Af8, Ef8, zsq, esq,
                                         lossAcc, doneCnt);
    mfma_score_kernel<<<dim3(16, 128), 256, 0, stream>>>(Af8, Ef8, keys);
    final_kernel<<<1024, 256, 0, stream>>>(keys, z, emb, zsq, esq,
                                           out, out + 4194305, out + 4194304,
                                           lossAcc, doneCnt);
}

// Round 10
// 190.797 us; speedup vs baseline: 1.0398x; 1.0398x over previous
//
#include <hip/hip_runtime.h>
#include <cstdint>
#include <cstddef>

#define N_PIX   16384
#define K_EMB   8192
#define DDIM    256

// ws layout (bytes)
#define WS_A8       0           // A fp8 chunk-major [128][8][4096]   4194304
#define WS_E8       4194304     // E fp8 (x8192) [64][8][4096]        2097152
#define WS_KEYS     6291456     // keys [32 subs][16384] uint2        4194304
#define WS_ZSQ      23068672    // 16384*4
#define WS_ESQ      23134208    // 8192*4
#define WS_LOSS     23166976    // 8
#define WS_CNT      23166984    // 4

typedef float f32x4 __attribute__((ext_vector_type(4)));

__device__ __forceinline__ unsigned int f32_sortable(float f) {
    unsigned int u = __float_as_uint(f);
    return (u & 0x80000000u) ? ~u : (u | 0x80000000u);
}

// fp32 -> OCP e4m3fn RNE (fallback path; handles subnormals)
__device__ __forceinline__ unsigned char f2fp8(float x) {
    unsigned ub = __float_as_uint(x);
    unsigned sgn = (ub >> 24) & 0x80u;
    unsigned b = ub & 0x7FFFFFFFu;
    unsigned out;
    if (__uint_as_float(b) < 0.015625f) {
        out = (unsigned)(int)rintf(__uint_as_float(b) * 512.0f);
    } else {
        unsigned r = b + 0x7FFFFu + ((b >> 20) & 1u);
        int er = (int)(r >> 23) - 127;
        out = (unsigned)(((er + 7) << 3) | ((r >> 20) & 7u));
    }
    return (unsigned char)(out | sgn);
}

#if defined(__has_builtin)
#if __has_builtin(__builtin_amdgcn_cvt_pk_fp8_f32)
#define HAVE_CVT_FP8 1
#endif
#if __has_builtin(__builtin_amdgcn_fmed3f)
#define HAVE_FMED3 1
#endif
#endif

__device__ __forceinline__ unsigned pack4_fp8(float a, float b, float c, float d) {
#ifdef HAVE_CVT_FP8
    int pk = 0;
    pk = __builtin_amdgcn_cvt_pk_fp8_f32(a, b, pk, false);
    pk = __builtin_amdgcn_cvt_pk_fp8_f32(c, d, pk, true);
    return (unsigned)pk;
#else
    return (unsigned)f2fp8(a) | ((unsigned)f2fp8(b) << 8)
         | ((unsigned)f2fp8(c) << 16) | ((unsigned)f2fp8(d) << 24);
#endif
}

__device__ __forceinline__ void async16(const unsigned char* g, unsigned char* l) {
    __builtin_amdgcn_global_load_lds(
        (const __attribute__((address_space(1))) void*)g,
        (__attribute__((address_space(3))) void*)l, 16, 0, 0);
}

// np pairwise-sum of squares over 256 contiguous LDS floats (one thread)
__device__ __forceinline__ float np_pairwise_sq256(const float* row) {
    float r[16];
#pragma unroll
    for (int j = 0; j < 16; ++j) r[j] = 0.f;
#pragma unroll
    for (int c = 0; c < 256; ++c) {
        float x  = row[c];
        float sq = __fmul_rn(x, x);
        int slot = ((c >> 7) << 3) | (c & 7);
        r[slot] = __fadd_rn(r[slot], sq);
    }
    float h0 = __fadd_rn(
        __fadd_rn(__fadd_rn(r[0], r[1]), __fadd_rn(r[2], r[3])),
        __fadd_rn(__fadd_rn(r[4], r[5]), __fadd_rn(r[6], r[7])));
    float h1 = __fadd_rn(
        __fadd_rn(__fadd_rn(r[8], r[9]), __fadd_rn(r[10], r[11])),
        __fadd_rn(__fadd_rn(r[12], r[13]), __fadd_rn(r[14], r[15])));
    return __fadd_rn(h0, h1);
}

// chunk-major byte offset for (row-in-128 r, byte-column c) within one
// 32 KB block: ks = c>>5, h = (c>>4)&1, s = h ^ ((r>>2)&1)
__device__ __forceinline__ size_t cm_addr(int r, int c) {
    int ks = c >> 5;
    int h  = (c >> 4) & 1;
    int s  = h ^ ((r >> 2) & 1);
    return (size_t)ks * 4096 + (size_t)r * 32 + s * 16 + (c & 15);
}

// ---------------------------------------------------------------- kernel 1
// unchanged from R4
__global__ __launch_bounds__(256) void prep_kernel(
        const float* __restrict__ z, const float* __restrict__ emb,
        unsigned char* __restrict__ Af8, unsigned char* __restrict__ Ef8,
        float* __restrict__ zsq, float* __restrict__ esq,
        double* __restrict__ lossAcc, unsigned* __restrict__ doneCnt) {
    __shared__ float tile[32][257];
    int blk = blockIdx.x;
    int t   = threadIdx.x;
    if (blk < 512) {
        int b   = blk >> 5;
        int hw0 = (blk & 31) * 32;
        const float* zb = z + (size_t)b * 262144 + hw0;
        int c0  = t >> 3;
        int px4 = t & 7;
#pragma unroll
        for (int cc = 0; cc < 8; ++cc) {
            int c = cc * 32 + c0;
            float4 v = *(const float4*)&zb[(size_t)c * 1024 + px4 * 4];
            tile[px4 * 4 + 0][c] = v.x;
            tile[px4 * 4 + 1][c] = v.y;
            tile[px4 * 4 + 2][c] = v.z;
            tile[px4 * 4 + 3][c] = v.w;
        }
        __syncthreads();
        int p0 = b * 1024 + hw0;
        int wv = t >> 6, lane = t & 63;
#pragma unroll
        for (int iter = 0; iter < 8; ++iter) {
            int pl = iter * 4 + wv;
            unsigned pk = pack4_fp8(tile[pl][lane * 4 + 0], tile[pl][lane * 4 + 1],
                                    tile[pl][lane * 4 + 2], tile[pl][lane * 4 + 3]);
            int p  = p0 + pl;
            int mb = p >> 7, r = p & 127;
            *(unsigned*)(Af8 + (size_t)mb * 32768 + cm_addr(r, lane * 4)) = pk;
        }
        if (t < 32) zsq[p0 + t] = np_pairwise_sq256(tile[t]);
        if (blk == 0 && t == 0) { *lossAcc = 0.0; *doneCnt = 0u; }
    } else {
        int k0 = (blk - 512) * 32;
        const float4* eg = (const float4*)(emb + (size_t)k0 * DDIM);
#pragma unroll
        for (int i = 0; i < 8; ++i) {
            int idx = i * 256 + t;
            int row = idx >> 6, c4 = idx & 63;
            float4 v = eg[idx];
            *(float4*)&tile[row][c4 * 4] = v;
        }
        __syncthreads();
#pragma unroll
        for (int i = 0; i < 8; ++i) {
            int idx = i * 256 + t;
            int row = idx >> 6, c4 = idx & 63;
            const float* rp = &tile[row][c4 * 4];
            int kg = k0 + row;
            int nb = kg >> 7, rr = kg & 127;
            *(unsigned*)(Ef8 + (size_t)nb * 32768 + cm_addr(rr, c4 * 4)) =
                pack4_fp8(rp[0] * 8192.0f, rp[1] * 8192.0f,
                          rp[2] * 8192.0f, rp[3] * 8192.0f);
        }
        if (t < 32) esq[k0 + t] = np_pairwise_sq256(tile[t]);
    }
}

// winner float (idx in low 13 mantissa bits) -> integer key
__device__ __forceinline__ unsigned pack_key(float w) {
    float uf = __builtin_fmaf(w, -512.0f, 262144.0f);
    uf = fminf(uf, 524287.0f);
    unsigned u = (unsigned)uf;
    return (u << 13) | (__float_as_uint(w) & 0x1FFFu);
}

// ---------------------------------------------------------------- kernel 2
// R10: T3-minimum pipeline done RIGHT (R9 scattered the issues inside the
// MFMA loop and regressed). Double-buffered Bs[2]; the 8 next-tile
// async16 are issued AS ONE BATCH at the top of each j-phase, BEFORE the
// MFMA burst; one barrier per j drains loads issued ~2500 cyc earlier
// (nearly free). A-fragments register-resident (R6). Selection top-2
// insert via v_med3_f32 (4 -> 3 VALU ops/element, identical results).
__global__ __launch_bounds__(256) void mfma_score_kernel(
        const unsigned char* __restrict__ Af8,
        const unsigned char* __restrict__ Ef8,
        unsigned int* __restrict__ keys) {
    union SM {
        unsigned char Bs[2][8][4096];    // 64 KB: E tiles, double-buffered
        struct { uint2 ep[128][33]; } e; // 33.8 KB, reused in epilogue
    };
    __shared__ SM sm;

    const int g  = blockIdx.x;      // 0..15
    const int mb = blockIdx.y;      // 0..127
    const int t = threadIdx.x;
    const int w = t >> 6, lane = t & 63;
    const int wm = w >> 1, wn = w & 1;
    const int quad = lane >> 4, l16 = lane & 15;

    // stage first E tile into Bs[0]
    {
        const unsigned char* Eg = Ef8 + (size_t)(g * 4) * 32768 + t * 16;
#pragma unroll
        for (int ks = 0; ks < 8; ++ks)
            async16(Eg + ks * 4096, &sm.Bs[0][ks][t * 16]);
    }

    int aaddr[4], baddr[4];
#pragma unroll
    for (int fi = 0; fi < 4; ++fi) {
        int row = wm * 64 + fi * 16 + l16;
        int gg  = (quad >> 1) ^ ((row >> 2) & 1);
        aaddr[fi] = row * 32 + gg * 16 + (quad & 1) * 8;
    }
#pragma unroll
    for (int fj = 0; fj < 4; ++fj) {
        int row = wn * 64 + fj * 16 + l16;
        int gg  = (quad >> 1) ^ ((row >> 2) & 1);
        baddr[fj] = row * 32 + gg * 16 + (quad & 1) * 8;
    }

    // A-fragments: one-time direct L2->reg load (R6; outside inner loop)
    long long afr[4][8];
    {
        const unsigned char* Agb = Af8 + (size_t)mb * 32768;
#pragma unroll
        for (int fi = 0; fi < 4; ++fi)
#pragma unroll
            for (int ks = 0; ks < 8; ++ks)
                afr[fi][ks] = *(const long long*)(Agb + ks * 4096 + aaddr[fi]);
    }

    const float NEGINF = __int_as_float(0xFF800000);
    float t2a[16], t2b[16];
#pragma unroll
    for (int i = 0; i < 16; ++i) { t2a[i] = NEGINF; t2b[i] = NEGINF; }

    __syncthreads();   // E0 staged (vmcnt(0) drain at barrier)

#pragma unroll 1
    for (int j = 0; j < 4; ++j) {
        const int cur = j & 1, nxt = cur ^ 1;

        // ---- issue next-tile stage batch FIRST (in flight during MFMAs)
        if (j < 3) {
            const unsigned char* Egn =
                Ef8 + (size_t)(g * 4 + j + 1) * 32768 + t * 16;
#pragma unroll
            for (int ks = 0; ks < 8; ++ks)
                async16(Egn + ks * 4096, &sm.Bs[nxt][ks][t * 16]);
        }

        f32x4 acc[4][4];
#pragma unroll
        for (int i = 0; i < 4; ++i)
#pragma unroll
            for (int jj = 0; jj < 4; ++jj)
#pragma unroll
                for (int r = 0; r < 4; ++r) acc[i][jj][r] = 0.f;

#pragma unroll
        for (int ks = 0; ks < 8; ++ks) {
            long long bfr[4];
#pragma unroll
            for (int fj = 0; fj < 4; ++fj)
                bfr[fj] = *(const long long*)&sm.Bs[cur][ks][baddr[fj]];
            __builtin_amdgcn_s_setprio(1);
#pragma unroll
            for (int fi = 0; fi < 4; ++fi)
#pragma unroll
                for (int fj = 0; fj < 4; ++fj)
                    acc[fi][fj] = __builtin_amdgcn_mfma_f32_16x16x32_fp8_fp8(
                        afr[fi][ks], bfr[fj], acc[fi][fj], 0, 0, 0);
            __builtin_amdgcn_s_setprio(0);
        }

        // selection (pure VALU; staged loads still in flight)
        const int nb = g * 4 + j;
        const unsigned idx0 = (unsigned)(nb * 128 + wn * 64 + l16);
#pragma unroll
        for (int fi = 0; fi < 4; ++fi) {
#pragma unroll
            for (int r = 0; r < 4; ++r) {
                const int ai = fi * 4 + r;
                float a0 = t2a[ai], b0 = t2b[ai];
#pragma unroll
                for (int fj = 0; fj < 4; ++fj) {
                    float v = acc[fi][fj][r];
                    float wv = __uint_as_float(
                        (__float_as_uint(v) & 0xFFFFE000u) | (idx0 + fj * 16));
#ifdef HAVE_FMED3
                    float bn = __builtin_amdgcn_fmed3f(a0, wv, b0);
                    a0 = fmaxf(a0, wv);
                    b0 = bn;
#else
                    float mn = fminf(a0, wv);
                    a0 = fmaxf(a0, wv);
                    b0 = fmaxf(b0, mn);
#endif
                }
                t2a[ai] = a0; t2b[ai] = b0;
            }
        }
        __syncthreads();   // drains stage batch (issued ~2500 cyc ago)
    }

    // epilogue: winners -> integer keys -> LDS -> per-(row,half) reduce
#pragma unroll
    for (int fi = 0; fi < 4; ++fi) {
#pragma unroll
        for (int r = 0; r < 4; ++r) {
            const int ai = fi * 4 + r;
            int row = wm * 64 + fi * 16 + quad * 4 + r;
            sm.e.ep[row][wn * 16 + l16] =
                make_uint2(pack_key(t2a[ai]), pack_key(t2b[ai]));
        }
    }
    __syncthreads();

    {
        int row = t >> 1, half = t & 1, h0 = half * 16;
        uint2 mv = sm.e.ep[row][h0];
#pragma unroll
        for (int i = 1; i < 16; ++i) {
            uint2 av = sm.e.ep[row][h0 + i];
            unsigned n0 = min(mv.x, av.x);
            unsigned n1 = min(max(mv.x, av.x), min(mv.y, av.y));
            mv.x = n0; mv.y = n1;
        }
        ((uint2*)keys)[(size_t)(g * 2 + half) * N_PIX + (mb * 128 + row)] = mv;
    }
}

// ---------------------------------------------------------------- kernel 3
// unchanged from R4 (parallel rescore)
__global__ __launch_bounds__(256) void final_kernel(
        const unsigned int* __restrict__ keys,
        const float* __restrict__ z, const float* __restrict__ emb,
        const float* __restrict__ zsq, const float* __restrict__ esq,
        float* __restrict__ out, float* __restrict__ idx_out,
        float* __restrict__ loss_out,
        double* __restrict__ lossAcc, unsigned* __restrict__ doneCnt) {
    __shared__ float ztile[16][260];
    __shared__ uint2 kt[16][33];
    __shared__ int   scand[16][64];
    __shared__ unsigned long long ckey[1024];
    __shared__ int   soff[17];
    __shared__ int   scnt[16];
    __shared__ int   pxmap[1024];
    __shared__ float szs[16];
    __shared__ int   sidx[16];

    int blk = blockIdx.x;                // 0..1023 = b*64 + hh
    int b = blk >> 6, hh = blk & 63;
    int t = threadIdx.x;
    int p0 = b * 1024 + hh * 16;
    const float* zb = z + (size_t)b * 262144 + hh * 16;
    {
        int px = t & 15, cb = t >> 4;
#pragma unroll
        for (int cc = 0; cc < 16; ++cc) {
            int c = cc * 16 + cb;
            ztile[px][c] = zb[(size_t)c * 1024 + px];
        }
    }
    {
        const uint2* kg = (const uint2*)keys;
#pragma unroll
        for (int itr = 0; itr < 2; ++itr) {
            int idx = itr * 256 + t;
            int px = idx & 15, hf = idx >> 4;
            kt[px][hf] = kg[(size_t)hf * N_PIX + p0 + px];
        }
    }
    if (t < 16) szs[t] = zsq[p0 + t];
    __syncthreads();

    // ---- Phase A: threshold + compact candidate lists
    {
        int wq = t >> 6, lane = t & 63;
#pragma unroll 1
        for (int i = 0; i < 4; ++i) {
            int px = wq * 4 + i;
            uint2 ka = (lane < 32) ? kt[px][lane] : make_uint2(~0u, ~0u);
            unsigned m = min(ka.x, ka.y);
#pragma unroll
            for (int off = 32; off >= 1; off >>= 1)
                m = min(m, (unsigned)__shfl_xor((int)m, off, 64));
            unsigned thr = (m >> 13) + 1600;   // margin 1600*2^-21 = 7.6e-4

            bool h0 = (lane < 32) && ((ka.x >> 13) <= thr);
            bool h1 = (lane < 32) && ((ka.y >> 13) <= thr);
            unsigned long long m0 = __ballot(h0);
            unsigned long long m1 = __ballot(h1);
            int c0 = __popcll(m0);
            unsigned long long below = (lane == 63) ? ~0ull >> 1
                                     : ((1ull << lane) - 1);
            if (h0) scand[px][__popcll(m0 & below)] = (int)(ka.x & 0x1FFFu);
            if (h1) scand[px][c0 + __popcll(m1 & below)] = (int)(ka.y & 0x1FFFu);
            if (lane == 0) scnt[px] = c0 + __popcll(m1);
        }
    }
    __syncthreads();

    // ---- scan counts -> soff (wave 0), then pxmap
    if (t < 64) {
        int v = (t < 16) ? scnt[t] : 0;
#pragma unroll
        for (int o = 1; o < 16; o <<= 1) {
            int u = __shfl_up(v, o, 64);
            if (t >= o) v += u;
        }
        if (t < 16) soff[t + 1] = v;
        if (t == 0) soff[0] = 0;
    }
    __syncthreads();
    int total = soff[16];
    for (int f = t; f < total; f += 256) {
        int lo = 0, hi = 15;
        while (lo < hi) {
            int mid = (lo + hi + 1) >> 1;
            if (soff[mid] <= f) lo = mid; else hi = mid - 1;
        }
        pxmap[f] = lo;
    }
    __syncthreads();

    // ---- Phase B: parallel rescore, one candidate per 16-lane group
    {
        int gid = t >> 4, l16 = t & 15;
        const float4* emb4 = (const float4*)emb;
#pragma unroll 1
        for (int f = gid; f < total; f += 16) {
            int px = pxmap[f];
            int k  = scand[px][f - soff[px]];
            double d = 0.0;
#pragma unroll
            for (int q = 0; q < 4; ++q) {
                float4 ev = emb4[(size_t)k * 64 + q * 16 + l16];
                const float* zp = &ztile[px][(q * 16 + l16) * 4];
                d += (double)zp[0] * ev.x + (double)zp[1] * ev.y
                   + (double)zp[2] * ev.z + (double)zp[3] * ev.w;
            }
#pragma unroll
            for (int o = 1; o < 16; o <<= 1) d += __shfl_xor(d, o, 64);
            if (l16 == 0) {
                float df = (float)d;
                float s  = __fsub_rn(__fadd_rn(szs[px], esq[k]),
                                     __fmul_rn(2.0f, df));
                ckey[f] = ((unsigned long long)f32_sortable(s) << 32)
                        | (unsigned)k;
            }
        }
    }
    __syncthreads();

    // ---- Phase C: per-pixel u64 min (16 threads each)
    {
        int cpx = t >> 4, ci = t & 15;
        unsigned long long best = ~0ull;
        for (int f = soff[cpx] + ci; f < soff[cpx + 1]; f += 16) {
            unsigned long long v = ckey[f];
            best = v < best ? v : best;
        }
#pragma unroll
        for (int o = 1; o < 16; o <<= 1) {
            unsigned long long ov =
                (unsigned long long)__shfl_xor((long long)best, o, 64);
            best = ov < best ? ov : best;
        }
        if (ci == 0) {
            int k = (int)(unsigned)(best & 0xffffffffu);
            sidx[cpx] = k;
            idx_out[p0 + cpx] = (float)k;
        }
    }
    __syncthreads();

    // ---- gather + loss (unchanged)
    int px2 = t & 15, cy = t >> 4;
    int kk = sidx[px2];
    const float* er = emb + (size_t)kk * DDIM;
    float* ob = out + (size_t)b * 262144 + hh * 16;
    float local = 0.f;
#pragma unroll 4
    for (int it = 0; it < 16; ++it) {
        int c = it * 16 + cy;
        float q = er[c];
        float d = q - ztile[px2][c];
        ob[(size_t)c * 1024 + px2] = q;
        local += d * d;
    }
#pragma unroll
    for (int off = 32; off >= 1; off >>= 1) local += __shfl_down(local, off, 64);
    __shared__ float wsum[4];
    if ((t & 63) == 0) wsum[t >> 6] = local;
    __syncthreads();
    if (t == 0) {
        double s = (double)wsum[0] + (double)wsum[1]
                 + (double)wsum[2] + (double)wsum[3];
        atomicAdd(lossAcc, s);
        __threadfence();
        unsigned old = atomicAdd(doneCnt, 1u);
        if (old == 1023u) {
            double tot = atomicAdd(lossAcc, 0.0);
            *loss_out = (float)(tot * (1.25 / 4194304.0));
        }
    }
}

// ----------------------------------------------------------------
extern "C" void kernel_launch(void* const* d_in, const int* in_sizes, int n_in,
                              void* d_out, int out_size, void* d_ws, size_t ws_size,
                              hipStream_t stream) {
    const float* z   = (const float*)d_in[0];
    const float* emb = (const float*)d_in[1];
    float* out = (float*)d_out;
    char* ws = (char*)d_ws;

    unsigned char* Af8 = (unsigned char*)(ws + WS_A8);
    unsigned char* Ef8 = (unsigned char*)(ws + WS_E8);
    unsigned int* keys = (unsigned int*)(ws + WS_KEYS);
    float* zsq      = (float*)(ws + WS_ZSQ);
    float* esq      = (float*)(ws + WS_ESQ);
    double* lossAcc = (double*)(ws + WS_LOSS);
    unsigned* doneCnt = (unsigned*)(ws + WS_CNT);

    prep_kernel<<<768, 256, 0, stream>>>(z, emb, Af8, Ef8, zsq, esq,
                                         lossAcc, doneCnt);
    mfma_score_kernel<<<dim3(16, 128), 256, 0, stream>>>(Af8, Ef8, keys);
    final_kernel<<<1024, 256, 0, stream>>>(keys, z, emb, zsq, esq,
                                           out, out + 4194305, out + 4194304,
                                           lossAcc, doneCnt);
}

// Round 11
// 187.101 us; speedup vs baseline: 1.0604x; 1.0198x over previous
//
#include <hip/hip_runtime.h>
#include <cstdint>
#include <cstddef>

#define N_PIX   16384
#define K_EMB   8192
#define DDIM    256

// ws layout (bytes)
// Af8: [mb=128][kk=4][r=128][64B]  (row r of pixel tile, k-range kk*64..+64)
// Ef8: same geometry, but 16B slots XOR-swizzled: slot s stored at s^((r>>1)&3)
#define WS_A8       0           // 4194304
#define WS_E8       4194304     // 2097152
#define WS_KEYS     6291456     // keys [32 pools][16384] uint2   4194304
#define WS_ZSQ      23068672    // 16384*4
#define WS_ESQ      23134208    // 8192*4
#define WS_LOSS     23166976    // 8
#define WS_CNT      23166984    // 4

typedef float f32x16 __attribute__((ext_vector_type(16)));
typedef int   i32x4  __attribute__((ext_vector_type(4)));
typedef int   i32x8  __attribute__((ext_vector_type(8)));

__device__ __forceinline__ unsigned int f32_sortable(float f) {
    unsigned int u = __float_as_uint(f);
    return (u & 0x80000000u) ? ~u : (u | 0x80000000u);
}

// fp32 -> OCP e4m3fn RNE (fallback path; handles subnormals)
__device__ __forceinline__ unsigned char f2fp8(float x) {
    unsigned ub = __float_as_uint(x);
    unsigned sgn = (ub >> 24) & 0x80u;
    unsigned b = ub & 0x7FFFFFFFu;
    unsigned out;
    if (__uint_as_float(b) < 0.015625f) {
        out = (unsigned)(int)rintf(__uint_as_float(b) * 512.0f);
    } else {
        unsigned r = b + 0x7FFFFu + ((b >> 20) & 1u);
        int er = (int)(r >> 23) - 127;
        out = (unsigned)(((er + 7) << 3) | ((r >> 20) & 7u));
    }
    return (unsigned char)(out | sgn);
}

#if defined(__has_builtin)
#if __has_builtin(__builtin_amdgcn_cvt_pk_fp8_f32)
#define HAVE_CVT_FP8 1
#endif
#if __has_builtin(__builtin_amdgcn_fmed3f)
#define HAVE_FMED3 1
#endif
#endif

__device__ __forceinline__ unsigned pack4_fp8(float a, float b, float c, float d) {
#ifdef HAVE_CVT_FP8
    int pk = 0;
    pk = __builtin_amdgcn_cvt_pk_fp8_f32(a, b, pk, false);
    pk = __builtin_amdgcn_cvt_pk_fp8_f32(c, d, pk, true);
    return (unsigned)pk;
#else
    return (unsigned)f2fp8(a) | ((unsigned)f2fp8(b) << 8)
         | ((unsigned)f2fp8(c) << 16) | ((unsigned)f2fp8(d) << 24);
#endif
}

__device__ __forceinline__ void async16(const unsigned char* g, unsigned char* l) {
    __builtin_amdgcn_global_load_lds(
        (const __attribute__((address_space(1))) void*)g,
        (__attribute__((address_space(3))) void*)l, 16, 0, 0);
}

// np pairwise-sum of squares over 256 contiguous LDS floats (one thread)
__device__ __forceinline__ float np_pairwise_sq256(const float* row) {
    float r[16];
#pragma unroll
    for (int j = 0; j < 16; ++j) r[j] = 0.f;
#pragma unroll
    for (int c = 0; c < 256; ++c) {
        float x  = row[c];
        float sq = __fmul_rn(x, x);
        int slot = ((c >> 7) << 3) | (c & 7);
        r[slot] = __fadd_rn(r[slot], sq);
    }
    float h0 = __fadd_rn(
        __fadd_rn(__fadd_rn(r[0], r[1]), __fadd_rn(r[2], r[3])),
        __fadd_rn(__fadd_rn(r[4], r[5]), __fadd_rn(r[6], r[7])));
    float h1 = __fadd_rn(
        __fadd_rn(__fadd_rn(r[8], r[9]), __fadd_rn(r[10], r[11])),
        __fadd_rn(__fadd_rn(r[12], r[13]), __fadd_rn(r[14], r[15])));
    return __fadd_rn(h0, h1);
}

// ---------------------------------------------------------------- kernel 1
// R11: writes the new fragrow-major layouts. A unswizzled; E slot-swizzled
// (s ^= (r>>1)&3 per 16B slot) so the score kernel's linear global_load_lds
// staging + swizzled ds_read_b128 is bank-spread (rule: pre-swizzle source).
__global__ __launch_bounds__(256) void prep_kernel(
        const float* __restrict__ z, const float* __restrict__ emb,
        unsigned char* __restrict__ Af8, unsigned char* __restrict__ Ef8,
        float* __restrict__ zsq, float* __restrict__ esq,
        double* __restrict__ lossAcc, unsigned* __restrict__ doneCnt) {
    __shared__ float tile[32][257];
    int blk = blockIdx.x;
    int t   = threadIdx.x;
    if (blk < 512) {
        int b   = blk >> 5;
        int hw0 = (blk & 31) * 32;
        const float* zb = z + (size_t)b * 262144 + hw0;
        int c0  = t >> 3;
        int px4 = t & 7;
#pragma unroll
        for (int cc = 0; cc < 8; ++cc) {
            int c = cc * 32 + c0;
            float4 v = *(const float4*)&zb[(size_t)c * 1024 + px4 * 4];
            tile[px4 * 4 + 0][c] = v.x;
            tile[px4 * 4 + 1][c] = v.y;
            tile[px4 * 4 + 2][c] = v.z;
            tile[px4 * 4 + 3][c] = v.w;
        }
        __syncthreads();
        int p0 = b * 1024 + hw0;
        int wv = t >> 6, lane = t & 63;
#pragma unroll
        for (int iter = 0; iter < 8; ++iter) {
            int pl = iter * 4 + wv;
            unsigned pk = pack4_fp8(tile[pl][lane * 4 + 0], tile[pl][lane * 4 + 1],
                                    tile[pl][lane * 4 + 2], tile[pl][lane * 4 + 3]);
            int p  = p0 + pl;
            int mbb = p >> 7, r = p & 127;
            int c = lane * 4;
            *(unsigned*)(Af8 + (size_t)mbb * 32768
                         + (c >> 6) * 8192 + r * 64 + (c & 63)) = pk;
        }
        if (t < 32) zsq[p0 + t] = np_pairwise_sq256(tile[t]);
        if (blk == 0 && t == 0) { *lossAcc = 0.0; *doneCnt = 0u; }
    } else {
        int k0 = (blk - 512) * 32;
        const float4* eg = (const float4*)(emb + (size_t)k0 * DDIM);
#pragma unroll
        for (int i = 0; i < 8; ++i) {
            int idx = i * 256 + t;
            int row = idx >> 6, c4 = idx & 63;
            float4 v = eg[idx];
            *(float4*)&tile[row][c4 * 4] = v;
        }
        __syncthreads();
#pragma unroll
        for (int i = 0; i < 8; ++i) {
            int idx = i * 256 + t;
            int row = idx >> 6, c4 = idx & 63;
            const float* rp = &tile[row][c4 * 4];
            int kg = k0 + row;
            int nbb = kg >> 7, rr = kg & 127;
            int c  = c4 * 4;
            int kk = c >> 6, kl = c & 63;
            int s  = kl >> 4;
            int pos = kk * 8192 + rr * 64
                    + ((s ^ ((rr >> 1) & 3)) << 4) + (kl & 15);
            *(unsigned*)(Ef8 + (size_t)nbb * 32768 + pos) =
                pack4_fp8(rp[0] * 8192.0f, rp[1] * 8192.0f,
                          rp[2] * 8192.0f, rp[3] * 8192.0f);
        }
        if (t < 32) esq[k0 + t] = np_pairwise_sq256(tile[t]);
    }
}

// winner float (idx in low 13 mantissa bits) -> integer key
__device__ __forceinline__ unsigned pack_key(float w) {
    float uf = __builtin_fmaf(w, -512.0f, 262144.0f);
    uf = fminf(uf, 524287.0f);
    unsigned u = (unsigned)uf;
    return (u << 13) | (__float_as_uint(w) & 0x1FFFu);
}

// ---------------------------------------------------------------- kernel 2
// R11: MX-scaled 32x32x64 f8f6f4 MFMA (scales = 0x7F -> x1.0 = plain fp8).
// 8x MACs/instruction at 2.3x rate: MFMA demand 80k -> 35k cyc/SIMD.
// Per wave: 2x2 tiles of 32x32, K=256 in 4 steps -> 16 MFMA per E-tile
// (was 128). A-frags in regs (R6); E staged via linear async16 into
// double-buffered LDS with R10's batch-issue-early pipeline; swizzled
// ds_read_b128. Epilogue: shfl_xor(16) merge -> ep[128][33] -> same
// 32-pool keys format; final kernel unchanged.
__global__ __launch_bounds__(256) void mfma_score_kernel(
        const unsigned char* __restrict__ Af8,
        const unsigned char* __restrict__ Ef8,
        unsigned int* __restrict__ keys) {
    union __align__(16) SM {
        unsigned char Bs[2][32768];      // 64 KB: E tiles (all K), dbuf
        struct { uint2 ep[128][33]; } e; // 33.8 KB, reused in epilogue
    };
    __shared__ SM sm;

    const int g  = blockIdx.x;      // 0..15
    const int mb = blockIdx.y;      // 0..127
    const int t = threadIdx.x;
    const int w = t >> 6, lane = t & 63;
    const int wm = w >> 1, wn = w & 1;
    const int l31 = lane & 31, h = lane >> 5;

    // stage first E tile into Bs[0] (linear copy of pre-swizzled Ef8)
    {
        const unsigned char* Eg = Ef8 + (size_t)(g * 4) * 32768 + t * 16;
#pragma unroll
        for (int ch = 0; ch < 8; ++ch)
            async16(Eg + ch * 4096, &sm.Bs[0][ch * 4096 + t * 16]);
    }

    // A-fragments: one-time direct L2->reg. lane holds row wm*64+rt*32+l31,
    // k-bytes kk*64 + h*32 .. +32 (contiguous per-lane chunk).
    i32x8 afr[2][4];
    {
        const unsigned char* Ab = Af8 + (size_t)mb * 32768;
#pragma unroll
        for (int rt = 0; rt < 2; ++rt) {
            int r = wm * 64 + rt * 32 + l31;
#pragma unroll
            for (int kk = 0; kk < 4; ++kk) {
                const unsigned char* p = Ab + kk * 8192 + r * 64 + h * 32;
                i32x4 lo = *(const i32x4*)p;
                i32x4 hi = *(const i32x4*)(p + 16);
                afr[rt][kk] = __builtin_shufflevector(lo, hi,
                                                      0, 1, 2, 3, 4, 5, 6, 7);
            }
        }
    }

    const float NEGINF = __int_as_float(0xFF800000);
    float t2a[2][16], t2b[2][16];
#pragma unroll
    for (int rt = 0; rt < 2; ++rt)
#pragma unroll
        for (int q = 0; q < 16; ++q) { t2a[rt][q] = NEGINF; t2b[rt][q] = NEGINF; }

    __syncthreads();   // E0 staged

#pragma unroll 1
    for (int j = 0; j < 4; ++j) {
        const int cur = j & 1, nxt = cur ^ 1;

        // issue next-tile stage batch FIRST (in flight during MFMAs)
        if (j < 3) {
            const unsigned char* Eg =
                Ef8 + (size_t)(g * 4 + j + 1) * 32768 + t * 16;
#pragma unroll
            for (int ch = 0; ch < 8; ++ch)
                async16(Eg + ch * 4096, &sm.Bs[nxt][ch * 4096 + t * 16]);
        }

        f32x16 acc[2][2];
#pragma unroll
        for (int rt = 0; rt < 2; ++rt)
#pragma unroll
            for (int ct = 0; ct < 2; ++ct)
#pragma unroll
                for (int q = 0; q < 16; ++q) acc[rt][ct][q] = 0.f;

#pragma unroll
        for (int kk = 0; kk < 4; ++kk) {
            i32x8 bf[2];
#pragma unroll
            for (int ct = 0; ct < 2; ++ct) {
                int c = wn * 64 + ct * 32 + l31;     // emb col
                int m = (c >> 1) & 3;                // slot swizzle
                int base = kk * 8192 + c * 64;
                int s0 = h * 2;
                i32x4 lo = *(const i32x4*)
                    &sm.Bs[cur][base + ((s0 ^ m) << 4)];
                i32x4 hi = *(const i32x4*)
                    &sm.Bs[cur][base + (((s0 + 1) ^ m) << 4)];
                bf[ct] = __builtin_shufflevector(lo, hi,
                                                 0, 1, 2, 3, 4, 5, 6, 7);
            }
            __builtin_amdgcn_s_setprio(1);
#pragma unroll
            for (int rt = 0; rt < 2; ++rt)
#pragma unroll
                for (int ct = 0; ct < 2; ++ct)
                    acc[rt][ct] =
                        __builtin_amdgcn_mfma_scale_f32_32x32x64_f8f6f4(
                            afr[rt][kk], bf[ct], acc[rt][ct],
                            0, 0,                 // cbsz=fp8, blgp=fp8
                            0, 0x7F7F7F7F,        // scale A = 1.0
                            0, 0x7F7F7F7F);       // scale B = 1.0
            __builtin_amdgcn_s_setprio(0);
        }

        // selection (pure VALU; staged loads still in flight)
        const int nb = g * 4 + j;
#pragma unroll
        for (int ct = 0; ct < 2; ++ct) {
            const unsigned idxc = (unsigned)(nb * 128 + wn * 64 + ct * 32 + l31);
#pragma unroll
            for (int rt = 0; rt < 2; ++rt) {
#pragma unroll
                for (int q = 0; q < 16; ++q) {
                    float v = acc[rt][ct][q];
                    float wv = __uint_as_float(
                        (__float_as_uint(v) & 0xFFFFE000u) | idxc);
                    float a0 = t2a[rt][q], b0 = t2b[rt][q];
#ifdef HAVE_FMED3
                    float bn = __builtin_amdgcn_fmed3f(a0, wv, b0);
                    t2a[rt][q] = fmaxf(a0, wv);
                    t2b[rt][q] = bn;
#else
                    float mn = fminf(a0, wv);
                    t2a[rt][q] = fmaxf(a0, wv);
                    t2b[rt][q] = fmaxf(b0, mn);
#endif
                }
            }
        }
        __syncthreads();   // drains stage batch (issued ~1 phase ago)
    }

    // epilogue: per row-slot, merge lane pairs (l, l^16) then ep reduce.
    // C/D layout: col = lane&31, row = (q&3) + 8*(q>>2) + 4*h.
#pragma unroll
    for (int rt = 0; rt < 2; ++rt) {
#pragma unroll
        for (int q = 0; q < 16; ++q) {
            unsigned ka = pack_key(t2a[rt][q]);
            unsigned kb = pack_key(t2b[rt][q]);
            unsigned pa = (unsigned)__shfl_xor((int)ka, 16, 64);
            unsigned pb = (unsigned)__shfl_xor((int)kb, 16, 64);
            unsigned n0 = min(ka, pa);
            unsigned n1 = min(max(ka, pa), min(kb, pb));
            if ((lane & 16) == 0) {
                int row = wm * 64 + rt * 32 + (q & 3) + 8 * (q >> 2) + 4 * h;
                sm.e.ep[row][wn * 16 + (lane & 15)] = make_uint2(n0, n1);
            }
        }
    }
    __syncthreads();

    {
        int row = t >> 1, half = t & 1, h0 = half * 16;
        uint2 mv = sm.e.ep[row][h0];
#pragma unroll
        for (int i = 1; i < 16; ++i) {
            uint2 av = sm.e.ep[row][h0 + i];
            unsigned n0 = min(mv.x, av.x);
            unsigned n1 = min(max(mv.x, av.x), min(mv.y, av.y));
            mv.x = n0; mv.y = n1;
        }
        ((uint2*)keys)[(size_t)(g * 2 + half) * N_PIX + (mb * 128 + row)] = mv;
    }
}

// ---------------------------------------------------------------- kernel 3
// unchanged from R4 (parallel rescore)
__global__ __launch_bounds__(256) void final_kernel(
        const unsigned int* __restrict__ keys,
        const float* __restrict__ z, const float* __restrict__ emb,
        const float* __restrict__ zsq, const float* __restrict__ esq,
        float* __restrict__ out, float* __restrict__ idx_out,
        float* __restrict__ loss_out,
        double* __restrict__ lossAcc, unsigned* __restrict__ doneCnt) {
    __shared__ float ztile[16][260];
    __shared__ uint2 kt[16][33];
    __shared__ int   scand[16][64];
    __shared__ unsigned long long ckey[1024];
    __shared__ int   soff[17];
    __shared__ int   scnt[16];
    __shared__ int   pxmap[1024];
    __shared__ float szs[16];
    __shared__ int   sidx[16];

    int blk = blockIdx.x;                // 0..1023 = b*64 + hh
    int b = blk >> 6, hh = blk & 63;
    int t = threadIdx.x;
    int p0 = b * 1024 + hh * 16;
    const float* zb = z + (size_t)b * 262144 + hh * 16;
    {
        int px = t & 15, cb = t >> 4;
#pragma unroll
        for (int cc = 0; cc < 16; ++cc) {
            int c = cc * 16 + cb;
            ztile[px][c] = zb[(size_t)c * 1024 + px];
        }
    }
    {
        const uint2* kg = (const uint2*)keys;
#pragma unroll
        for (int itr = 0; itr < 2; ++itr) {
            int idx = itr * 256 + t;
            int px = idx & 15, hf = idx >> 4;
            kt[px][hf] = kg[(size_t)hf * N_PIX + p0 + px];
        }
    }
    if (t < 16) szs[t] = zsq[p0 + t];
    __syncthreads();

    // ---- Phase A: threshold + compact candidate lists
    {
        int wq = t >> 6, lane = t & 63;
#pragma unroll 1
        for (int i = 0; i < 4; ++i) {
            int px = wq * 4 + i;
            uint2 ka = (lane < 32) ? kt[px][lane] : make_uint2(~0u, ~0u);
            unsigned m = min(ka.x, ka.y);
#pragma unroll
            for (int off = 32; off >= 1; off >>= 1)
                m = min(m, (unsigned)__shfl_xor((int)m, off, 64));
            unsigned thr = (m >> 13) + 1600;   // margin 1600*2^-21 = 7.6e-4

            bool h0 = (lane < 32) && ((ka.x >> 13) <= thr);
            bool h1 = (lane < 32) && ((ka.y >> 13) <= thr);
            unsigned long long m0 = __ballot(h0);
            unsigned long long m1 = __ballot(h1);
            int c0 = __popcll(m0);
            unsigned long long below = (lane == 63) ? ~0ull >> 1
                                     : ((1ull << lane) - 1);
            if (h0) scand[px][__popcll(m0 & below)] = (int)(ka.x & 0x1FFFu);
            if (h1) scand[px][c0 + __popcll(m1 & below)] = (int)(ka.y & 0x1FFFu);
            if (lane == 0) scnt[px] = c0 + __popcll(m1);
        }
    }
    __syncthreads();

    // ---- scan counts -> soff (wave 0), then pxmap
    if (t < 64) {
        int v = (t < 16) ? scnt[t] : 0;
#pragma unroll
        for (int o = 1; o < 16; o <<= 1) {
            int u = __shfl_up(v, o, 64);
            if (t >= o) v += u;
        }
        if (t < 16) soff[t + 1] = v;
        if (t == 0) soff[0] = 0;
    }
    __syncthreads();
    int total = soff[16];
    for (int f = t; f < total; f += 256) {
        int lo = 0, hi = 15;
        while (lo < hi) {
            int mid = (lo + hi + 1) >> 1;
            if (soff[mid] <= f) lo = mid; else hi = mid - 1;
        }
        pxmap[f] = lo;
    }
    __syncthreads();

    // ---- Phase B: parallel rescore, one candidate per 16-lane group
    {
        int gid = t >> 4, l16 = t & 15;
        const float4* emb4 = (const float4*)emb;
#pragma unroll 1
        for (int f = gid; f < total; f += 16) {
            int px = pxmap[f];
            int k  = scand[px][f - soff[px]];
            double d = 0.0;
#pragma unroll
            for (int q = 0; q < 4; ++q) {
                float4 ev = emb4[(size_t)k * 64 + q * 16 + l16];
                const float* zp = &ztile[px][(q * 16 + l16) * 4];
                d += (double)zp[0] * ev.x + (double)zp[1] * ev.y
                   + (double)zp[2] * ev.z + (double)zp[3] * ev.w;
            }
#pragma unroll
            for (int o = 1; o < 16; o <<= 1) d += __shfl_xor(d, o, 64);
            if (l16 == 0) {
                float df = (float)d;
                float s  = __fsub_rn(__fadd_rn(szs[px], esq[k]),
                                     __fmul_rn(2.0f, df));
                ckey[f] = ((unsigned long long)f32_sortable(s) << 32)
                        | (unsigned)k;
            }
        }
    }
    __syncthreads();

    // ---- Phase C: per-pixel u64 min (16 threads each)
    {
        int cpx = t >> 4, ci = t & 15;
        unsigned long long best = ~0ull;
        for (int f = soff[cpx] + ci; f < soff[cpx + 1]; f += 16) {
            unsigned long long v = ckey[f];
            best = v < best ? v : best;
        }
#pragma unroll
        for (int o = 1; o < 16; o <<= 1) {
            unsigned long long ov =
                (unsigned long long)__shfl_xor((long long)best, o, 64);
            best = ov < best ? ov : best;
        }
        if (ci == 0) {
            int k = (int)(unsigned)(best & 0xffffffffu);
            sidx[cpx] = k;
            idx_out[p0 + cpx] = (float)k;
        }
    }
    __syncthreads();

    // ---- gather + loss (unchanged)
    int px2 = t & 15, cy = t >> 4;
    int kk = sidx[px2];
    const float* er = emb + (size_t)kk * DDIM;
    float* ob = out + (size_t)b * 262144 + hh * 16;
    float local = 0.f;
#pragma unroll 4
    for (int it = 0; it < 16; ++it) {
        int c = it * 16 + cy;
        float q = er[c];
        float d = q - ztile[px2][c];
        ob[(size_t)c * 1024 + px2] = q;
        local += d * d;
    }
#pragma unroll
    for (int off = 32; off >= 1; off >>= 1) local += __shfl_down(local, off, 64);
    __shared__ float wsum[4];
    if ((t & 63) == 0) wsum[t >> 6] = local;
    __syncthreads();
    if (t == 0) {
        double s = (double)wsum[0] + (double)wsum[1]
                 + (double)wsum[2] + (double)wsum[3];
        atomicAdd(lossAcc, s);
        __threadfence();
        unsigned old = atomicAdd(doneCnt, 1u);
        if (old == 1023u) {
            double tot = atomicAdd(lossAcc, 0.0);
            *loss_out = (float)(tot * (1.25 / 4194304.0));
        }
    }
}

// ----------------------------------------------------------------
extern "C" void kernel_launch(void* const* d_in, const int* in_sizes, int n_in,
                              void* d_out, int out_size, void* d_ws, size_t ws_size,
                              hipStream_t stream) {
    const float* z   = (const float*)d_in[0];
    const float* emb = (const float*)d_in[1];
    float* out = (float*)d_out;
    char* ws = (char*)d_ws;

    unsigned char* Af8 = (unsigned char*)(ws + WS_A8);
    unsigned char* Ef8 = (unsigned char*)(ws + WS_E8);
    unsigned int* keys = (unsigned int*)(ws + WS_KEYS);
    float* zsq      = (float*)(ws + WS_ZSQ);
    float* esq      = (float*)(ws + WS_ESQ);
    double* lossAcc = (double*)(ws + WS_LOSS);
    unsigned* doneCnt = (unsigned*)(ws + WS_CNT);

    prep_kernel<<<768, 256, 0, stream>>>(z, emb, Af8, Ef8, zsq, esq,
                                         lossAcc, doneCnt);
    mfma_score_kernel<<<dim3(16, 128), 256, 0, stream>>>(Af8, Ef8, keys);
    final_kernel<<<1024, 256, 0, stream>>>(keys, z, emb, zsq, esq,
                                           out, out + 4194305, out + 4194304,
                                           lossAcc, doneCnt);
}

// Round 12
// 170.251 us; speedup vs baseline: 1.1653x; 1.0990x over previous
//
#include <hip/hip_runtime.h>
#include <cstdint>
#include <cstddef>

#define N_PIX   16384
#define K_EMB   8192
#define DDIM    256

// ws layout (bytes)
// Af8: [mb=128][kk=4][r=128][64B]  (row r of pixel tile, k-range kk*64..+64)
// Ef8: same geometry, but 16B slots XOR-swizzled: slot s stored at s^((r>>1)&3)
#define WS_A8       0           // 4194304
#define WS_E8       4194304     // 2097152
#define WS_KEYS     6291456     // keys [32 pools][16384] uint2   4194304
#define WS_ZSQ      23068672    // 16384*4
#define WS_ESQ      23134208    // 8192*4
#define WS_LOSS     23166976    // 8
#define WS_CNT      23166984    // 4

typedef float f32x16 __attribute__((ext_vector_type(16)));
typedef int   i32x4  __attribute__((ext_vector_type(4)));
typedef int   i32x8  __attribute__((ext_vector_type(8)));

__device__ __forceinline__ unsigned int f32_sortable(float f) {
    unsigned int u = __float_as_uint(f);
    return (u & 0x80000000u) ? ~u : (u | 0x80000000u);
}

// fp32 -> OCP e4m3fn RNE (fallback path; handles subnormals)
__device__ __forceinline__ unsigned char f2fp8(float x) {
    unsigned ub = __float_as_uint(x);
    unsigned sgn = (ub >> 24) & 0x80u;
    unsigned b = ub & 0x7FFFFFFFu;
    unsigned out;
    if (__uint_as_float(b) < 0.015625f) {
        out = (unsigned)(int)rintf(__uint_as_float(b) * 512.0f);
    } else {
        unsigned r = b + 0x7FFFFu + ((b >> 20) & 1u);
        int er = (int)(r >> 23) - 127;
        out = (unsigned)(((er + 7) << 3) | ((r >> 20) & 7u));
    }
    return (unsigned char)(out | sgn);
}

#if defined(__has_builtin)
#if __has_builtin(__builtin_amdgcn_cvt_pk_fp8_f32)
#define HAVE_CVT_FP8 1
#endif
#if __has_builtin(__builtin_amdgcn_fmed3f)
#define HAVE_FMED3 1
#endif
#endif

__device__ __forceinline__ unsigned pack4_fp8(float a, float b, float c, float d) {
#ifdef HAVE_CVT_FP8
    int pk = 0;
    pk = __builtin_amdgcn_cvt_pk_fp8_f32(a, b, pk, false);
    pk = __builtin_amdgcn_cvt_pk_fp8_f32(c, d, pk, true);
    return (unsigned)pk;
#else
    return (unsigned)f2fp8(a) | ((unsigned)f2fp8(b) << 8)
         | ((unsigned)f2fp8(c) << 16) | ((unsigned)f2fp8(d) << 24);
#endif
}

__device__ __forceinline__ void async16(const unsigned char* g, unsigned char* l) {
    __builtin_amdgcn_global_load_lds(
        (const __attribute__((address_space(1))) void*)g,
        (__attribute__((address_space(3))) void*)l, 16, 0, 0);
}

// ---------------------------------------------------------------- kernel 1
// R12: np-pairwise sum-of-squares WAVE-PARALLELIZED (bit-identical).
// Original: 32 threads x 256 serial iters (7.5 waves idle). Now: 512
// independent 16-element chains (2 per thread; same per-slot order),
// then the exact 16-leaf tree on t<32. Layouts unchanged from R11.
__global__ __launch_bounds__(256) void prep_kernel(
        const float* __restrict__ z, const float* __restrict__ emb,
        unsigned char* __restrict__ Af8, unsigned char* __restrict__ Ef8,
        float* __restrict__ zsq, float* __restrict__ esq,
        double* __restrict__ lossAcc, unsigned* __restrict__ doneCnt) {
    __shared__ float tile[32][257];
    __shared__ float sqs[32][17];
    int blk = blockIdx.x;
    int t   = threadIdx.x;
    if (blk < 512) {
        int b   = blk >> 5;
        int hw0 = (blk & 31) * 32;
        const float* zb = z + (size_t)b * 262144 + hw0;
        int c0  = t >> 3;
        int px4 = t & 7;
#pragma unroll
        for (int cc = 0; cc < 8; ++cc) {
            int c = cc * 32 + c0;
            float4 v = *(const float4*)&zb[(size_t)c * 1024 + px4 * 4];
            tile[px4 * 4 + 0][c] = v.x;
            tile[px4 * 4 + 1][c] = v.y;
            tile[px4 * 4 + 2][c] = v.z;
            tile[px4 * 4 + 3][c] = v.w;
        }
        __syncthreads();
        int p0 = b * 1024 + hw0;
        int wv = t >> 6, lane = t & 63;
#pragma unroll
        for (int iter = 0; iter < 8; ++iter) {
            int pl = iter * 4 + wv;
            unsigned pk = pack4_fp8(tile[pl][lane * 4 + 0], tile[pl][lane * 4 + 1],
                                    tile[pl][lane * 4 + 2], tile[pl][lane * 4 + 3]);
            int p  = p0 + pl;
            int mbb = p >> 7, r = p & 127;
            int c = lane * 4;
            *(unsigned*)(Af8 + (size_t)mbb * 32768
                         + (c >> 6) * 8192 + r * 64 + (c & 63)) = pk;
        }
        // wave-parallel sq: thread (row = t>>3, s0 = t&7) does slots s0, s0+8
        {
            int row = t >> 3, s0 = t & 7;
            const float* rp = tile[row];
            float a0 = 0.f, a1 = 0.f;
#pragma unroll
            for (int i = 0; i < 16; ++i) {
                float x0 = rp[s0 + 8 * i];
                a0 = __fadd_rn(a0, __fmul_rn(x0, x0));
            }
#pragma unroll
            for (int i = 0; i < 16; ++i) {
                float x1 = rp[128 + s0 + 8 * i];
                a1 = __fadd_rn(a1, __fmul_rn(x1, x1));
            }
            sqs[row][s0]     = a0;
            sqs[row][s0 + 8] = a1;
        }
        __syncthreads();
        if (t < 32) {
            const float* r = sqs[t];
            float h0 = __fadd_rn(
                __fadd_rn(__fadd_rn(r[0], r[1]), __fadd_rn(r[2], r[3])),
                __fadd_rn(__fadd_rn(r[4], r[5]), __fadd_rn(r[6], r[7])));
            float h1 = __fadd_rn(
                __fadd_rn(__fadd_rn(r[8], r[9]), __fadd_rn(r[10], r[11])),
                __fadd_rn(__fadd_rn(r[12], r[13]), __fadd_rn(r[14], r[15])));
            zsq[p0 + t] = __fadd_rn(h0, h1);
        }
        if (blk == 0 && t == 0) { *lossAcc = 0.0; *doneCnt = 0u; }
    } else {
        int k0 = (blk - 512) * 32;
        const float4* eg = (const float4*)(emb + (size_t)k0 * DDIM);
#pragma unroll
        for (int i = 0; i < 8; ++i) {
            int idx = i * 256 + t;
            int row = idx >> 6, c4 = idx & 63;
            float4 v = eg[idx];
            *(float4*)&tile[row][c4 * 4] = v;
        }
        __syncthreads();
#pragma unroll
        for (int i = 0; i < 8; ++i) {
            int idx = i * 256 + t;
            int row = idx >> 6, c4 = idx & 63;
            const float* rp = &tile[row][c4 * 4];
            int kg = k0 + row;
            int nbb = kg >> 7, rr = kg & 127;
            int c  = c4 * 4;
            int kk = c >> 6, kl = c & 63;
            int s  = kl >> 4;
            int pos = kk * 8192 + rr * 64
                    + ((s ^ ((rr >> 1) & 3)) << 4) + (kl & 15);
            *(unsigned*)(Ef8 + (size_t)nbb * 32768 + pos) =
                pack4_fp8(rp[0] * 8192.0f, rp[1] * 8192.0f,
                          rp[2] * 8192.0f, rp[3] * 8192.0f);
        }
        // wave-parallel sq (identical scheme)
        {
            int row = t >> 3, s0 = t & 7;
            const float* rp = tile[row];
            float a0 = 0.f, a1 = 0.f;
#pragma unroll
            for (int i = 0; i < 16; ++i) {
                float x0 = rp[s0 + 8 * i];
                a0 = __fadd_rn(a0, __fmul_rn(x0, x0));
            }
#pragma unroll
            for (int i = 0; i < 16; ++i) {
                float x1 = rp[128 + s0 + 8 * i];
                a1 = __fadd_rn(a1, __fmul_rn(x1, x1));
            }
            sqs[row][s0]     = a0;
            sqs[row][s0 + 8] = a1;
        }
        __syncthreads();
        if (t < 32) {
            const float* r = sqs[t];
            float h0 = __fadd_rn(
                __fadd_rn(__fadd_rn(r[0], r[1]), __fadd_rn(r[2], r[3])),
                __fadd_rn(__fadd_rn(r[4], r[5]), __fadd_rn(r[6], r[7])));
            float h1 = __fadd_rn(
                __fadd_rn(__fadd_rn(r[8], r[9]), __fadd_rn(r[10], r[11])),
                __fadd_rn(__fadd_rn(r[12], r[13]), __fadd_rn(r[14], r[15])));
            esq[k0 + t] = __fadd_rn(h0, h1);
        }
    }
}

// winner float (idx in low 13 mantissa bits) -> integer key
__device__ __forceinline__ unsigned pack_key(float w) {
    float uf = __builtin_fmaf(w, -512.0f, 262144.0f);
    uf = fminf(uf, 524287.0f);
    unsigned u = (unsigned)uf;
    return (u << 13) | (__float_as_uint(w) & 0x1FFFu);
}

// ---------------------------------------------------------------- kernel 2
// unchanged from R11 (MX-scaled 32x32x64, verified: 64.9 us, absmax OK)
__global__ __launch_bounds__(256) void mfma_score_kernel(
        const unsigned char* __restrict__ Af8,
        const unsigned char* __restrict__ Ef8,
        unsigned int* __restrict__ keys) {
    union __align__(16) SM {
        unsigned char Bs[2][32768];      // 64 KB: E tiles (all K), dbuf
        struct { uint2 ep[128][33]; } e; // 33.8 KB, reused in epilogue
    };
    __shared__ SM sm;

    const int g  = blockIdx.x;      // 0..15
    const int mb = blockIdx.y;      // 0..127
    const int t = threadIdx.x;
    const int w = t >> 6, lane = t & 63;
    const int wm = w >> 1, wn = w & 1;
    const int l31 = lane & 31, h = lane >> 5;

    {
        const unsigned char* Eg = Ef8 + (size_t)(g * 4) * 32768 + t * 16;
#pragma unroll
        for (int ch = 0; ch < 8; ++ch)
            async16(Eg + ch * 4096, &sm.Bs[0][ch * 4096 + t * 16]);
    }

    i32x8 afr[2][4];
    {
        const unsigned char* Ab = Af8 + (size_t)mb * 32768;
#pragma unroll
        for (int rt = 0; rt < 2; ++rt) {
            int r = wm * 64 + rt * 32 + l31;
#pragma unroll
            for (int kk = 0; kk < 4; ++kk) {
                const unsigned char* p = Ab + kk * 8192 + r * 64 + h * 32;
                i32x4 lo = *(const i32x4*)p;
                i32x4 hi = *(const i32x4*)(p + 16);
                afr[rt][kk] = __builtin_shufflevector(lo, hi,
                                                      0, 1, 2, 3, 4, 5, 6, 7);
            }
        }
    }

    const float NEGINF = __int_as_float(0xFF800000);
    float t2a[2][16], t2b[2][16];
#pragma unroll
    for (int rt = 0; rt < 2; ++rt)
#pragma unroll
        for (int q = 0; q < 16; ++q) { t2a[rt][q] = NEGINF; t2b[rt][q] = NEGINF; }

    __syncthreads();   // E0 staged

#pragma unroll 1
    for (int j = 0; j < 4; ++j) {
        const int cur = j & 1, nxt = cur ^ 1;

        if (j < 3) {
            const unsigned char* Eg =
                Ef8 + (size_t)(g * 4 + j + 1) * 32768 + t * 16;
#pragma unroll
            for (int ch = 0; ch < 8; ++ch)
                async16(Eg + ch * 4096, &sm.Bs[nxt][ch * 4096 + t * 16]);
        }

        f32x16 acc[2][2];
#pragma unroll
        for (int rt = 0; rt < 2; ++rt)
#pragma unroll
            for (int ct = 0; ct < 2; ++ct)
#pragma unroll
                for (int q = 0; q < 16; ++q) acc[rt][ct][q] = 0.f;

#pragma unroll
        for (int kk = 0; kk < 4; ++kk) {
            i32x8 bf[2];
#pragma unroll
            for (int ct = 0; ct < 2; ++ct) {
                int c = wn * 64 + ct * 32 + l31;
                int m = (c >> 1) & 3;
                int base = kk * 8192 + c * 64;
                int s0 = h * 2;
                i32x4 lo = *(const i32x4*)
                    &sm.Bs[cur][base + ((s0 ^ m) << 4)];
                i32x4 hi = *(const i32x4*)
                    &sm.Bs[cur][base + (((s0 + 1) ^ m) << 4)];
                bf[ct] = __builtin_shufflevector(lo, hi,
                                                 0, 1, 2, 3, 4, 5, 6, 7);
            }
            __builtin_amdgcn_s_setprio(1);
#pragma unroll
            for (int rt = 0; rt < 2; ++rt)
#pragma unroll
                for (int ct = 0; ct < 2; ++ct)
                    acc[rt][ct] =
                        __builtin_amdgcn_mfma_scale_f32_32x32x64_f8f6f4(
                            afr[rt][kk], bf[ct], acc[rt][ct],
                            0, 0,
                            0, 0x7F7F7F7F,
                            0, 0x7F7F7F7F);
            __builtin_amdgcn_s_setprio(0);
        }

        const int nb = g * 4 + j;
#pragma unroll
        for (int ct = 0; ct < 2; ++ct) {
            const unsigned idxc = (unsigned)(nb * 128 + wn * 64 + ct * 32 + l31);
#pragma unroll
            for (int rt = 0; rt < 2; ++rt) {
#pragma unroll
                for (int q = 0; q < 16; ++q) {
                    float v = acc[rt][ct][q];
                    float wv = __uint_as_float(
                        (__float_as_uint(v) & 0xFFFFE000u) | idxc);
                    float a0 = t2a[rt][q], b0 = t2b[rt][q];
#ifdef HAVE_FMED3
                    float bn = __builtin_amdgcn_fmed3f(a0, wv, b0);
                    t2a[rt][q] = fmaxf(a0, wv);
                    t2b[rt][q] = bn;
#else
                    float mn = fminf(a0, wv);
                    t2a[rt][q] = fmaxf(a0, wv);
                    t2b[rt][q] = fmaxf(b0, mn);
#endif
                }
            }
        }
        __syncthreads();
    }

#pragma unroll
    for (int rt = 0; rt < 2; ++rt) {
#pragma unroll
        for (int q = 0; q < 16; ++q) {
            unsigned ka = pack_key(t2a[rt][q]);
            unsigned kb = pack_key(t2b[rt][q]);
            unsigned pa = (unsigned)__shfl_xor((int)ka, 16, 64);
            unsigned pb = (unsigned)__shfl_xor((int)kb, 16, 64);
            unsigned n0 = min(ka, pa);
            unsigned n1 = min(max(ka, pa), min(kb, pb));
            if ((lane & 16) == 0) {
                int row = wm * 64 + rt * 32 + (q & 3) + 8 * (q >> 2) + 4 * h;
                sm.e.ep[row][wn * 16 + (lane & 15)] = make_uint2(n0, n1);
            }
        }
    }
    __syncthreads();

    {
        int row = t >> 1, half = t & 1, h0 = half * 16;
        uint2 mv = sm.e.ep[row][h0];
#pragma unroll
        for (int i = 1; i < 16; ++i) {
            uint2 av = sm.e.ep[row][h0 + i];
            unsigned n0 = min(mv.x, av.x);
            unsigned n1 = min(max(mv.x, av.x), min(mv.y, av.y));
            mv.x = n0; mv.y = n1;
        }
        ((uint2*)keys)[(size_t)(g * 2 + half) * N_PIX + (mb * 128 + row)] = mv;
    }
}

// ---------------------------------------------------------------- kernel 3
// R12: 32-px blocks (512 total). z-loads float4 (128B segments), out
// stores 128B segments (was 64B scalar), candidate structures widened:
// scand ushort[32][64], ckey[2048], 2-pass Phase C. Numerics identical.
__global__ __launch_bounds__(256) void final_kernel(
        const unsigned int* __restrict__ keys,
        const float* __restrict__ z, const float* __restrict__ emb,
        const float* __restrict__ zsq, const float* __restrict__ esq,
        float* __restrict__ out, float* __restrict__ idx_out,
        float* __restrict__ loss_out,
        double* __restrict__ lossAcc, unsigned* __restrict__ doneCnt) {
    __shared__ float ztile[32][257];            // 32.9 KB
    __shared__ uint2 kt[32][33];                // 8.4 KB
    __shared__ unsigned short scand[32][64];    // 4 KB
    __shared__ unsigned long long ckey[2048];   // 16 KB
    __shared__ int   soff[33];
    __shared__ int   scnt[32];
    __shared__ unsigned char pxmap[2048];       // 2 KB
    __shared__ float szs[32];
    __shared__ int   sidx[32];

    int blk = blockIdx.x;                // 0..511 = b*32 + hh2
    int b = blk >> 5, hh2 = blk & 31;
    int t = threadIdx.x;
    int p0 = b * 1024 + hh2 * 32;
    const float* zb = z + (size_t)b * 262144 + hh2 * 32;
    {
        int c0 = t >> 3, px4 = t & 7;
#pragma unroll
        for (int cc = 0; cc < 8; ++cc) {
            int c = cc * 32 + c0;
            float4 v = *(const float4*)&zb[(size_t)c * 1024 + px4 * 4];
            ztile[px4 * 4 + 0][c] = v.x;
            ztile[px4 * 4 + 1][c] = v.y;
            ztile[px4 * 4 + 2][c] = v.z;
            ztile[px4 * 4 + 3][c] = v.w;
        }
    }
    {
        const uint2* kg = (const uint2*)keys;
#pragma unroll
        for (int itr = 0; itr < 4; ++itr) {
            int idx = itr * 256 + t;           // 0..1023
            int px = idx & 31, hf = idx >> 5;  // hf 0..31
            kt[px][hf] = kg[(size_t)hf * N_PIX + p0 + px];
        }
    }
    if (t < 32) szs[t] = zsq[p0 + t];
    __syncthreads();

    // ---- Phase A: threshold + compact candidate lists (4 waves x 8 px)
    {
        int wq = t >> 6, lane = t & 63;
#pragma unroll 1
        for (int i = 0; i < 8; ++i) {
            int px = wq * 8 + i;
            uint2 ka = (lane < 32) ? kt[px][lane] : make_uint2(~0u, ~0u);
            unsigned m = min(ka.x, ka.y);
#pragma unroll
            for (int off = 32; off >= 1; off >>= 1)
                m = min(m, (unsigned)__shfl_xor((int)m, off, 64));
            unsigned thr = (m >> 13) + 1600;   // margin 1600*2^-21 = 7.6e-4

            bool h0 = (lane < 32) && ((ka.x >> 13) <= thr);
            bool h1 = (lane < 32) && ((ka.y >> 13) <= thr);
            unsigned long long m0 = __ballot(h0);
            unsigned long long m1 = __ballot(h1);
            int c0 = __popcll(m0);
            unsigned long long below = (lane == 63) ? ~0ull >> 1
                                     : ((1ull << lane) - 1);
            if (h0) scand[px][__popcll(m0 & below)] =
                (unsigned short)(ka.x & 0x1FFFu);
            if (h1) scand[px][c0 + __popcll(m1 & below)] =
                (unsigned short)(ka.y & 0x1FFFu);
            if (lane == 0) scnt[px] = c0 + __popcll(m1);
        }
    }
    __syncthreads();

    // ---- scan 32 counts -> soff (wave 0), then pxmap
    if (t < 64) {
        int v = (t < 32) ? scnt[t] : 0;
#pragma unroll
        for (int o = 1; o < 32; o <<= 1) {
            int u = __shfl_up(v, o, 64);
            if (t >= o) v += u;
        }
        if (t < 32) soff[t + 1] = v;
        if (t == 0) soff[0] = 0;
    }
    __syncthreads();
    int total = soff[32];
    for (int f = t; f < total; f += 256) {
        int lo = 0, hi = 31;
        while (lo < hi) {
            int mid = (lo + hi + 1) >> 1;
            if (soff[mid] <= f) lo = mid; else hi = mid - 1;
        }
        pxmap[f] = (unsigned char)lo;
    }
    __syncthreads();

    // ---- Phase B: parallel rescore, one candidate per 16-lane group
    {
        int gid = t >> 4, l16 = t & 15;
        const float4* emb4 = (const float4*)emb;
#pragma unroll 1
        for (int f = gid; f < total; f += 16) {
            int px = pxmap[f];
            int k  = scand[px][f - soff[px]];
            double d = 0.0;
#pragma unroll
            for (int q = 0; q < 4; ++q) {
                float4 ev = emb4[(size_t)k * 64 + q * 16 + l16];
                const float* zp = &ztile[px][(q * 16 + l16) * 4];
                d += (double)zp[0] * ev.x + (double)zp[1] * ev.y
                   + (double)zp[2] * ev.z + (double)zp[3] * ev.w;
            }
#pragma unroll
            for (int o = 1; o < 16; o <<= 1) d += __shfl_xor(d, o, 64);
            if (l16 == 0) {
                float df = (float)d;
                float s  = __fsub_rn(__fadd_rn(szs[px], esq[k]),
                                     __fmul_rn(2.0f, df));
                ckey[f] = ((unsigned long long)f32_sortable(s) << 32)
                        | (unsigned)k;
            }
        }
    }
    __syncthreads();

    // ---- Phase C: per-pixel u64 min (16 threads each, 2 passes)
    {
        int ci = t & 15;
#pragma unroll
        for (int pass = 0; pass < 2; ++pass) {
            int cpx = (t >> 4) + pass * 16;
            unsigned long long best = ~0ull;
            for (int f = soff[cpx] + ci; f < soff[cpx + 1]; f += 16) {
                unsigned long long v = ckey[f];
                best = v < best ? v : best;
            }
#pragma unroll
            for (int o = 1; o < 16; o <<= 1) {
                unsigned long long ov =
                    (unsigned long long)__shfl_xor((long long)best, o, 64);
                best = ov < best ? ov : best;
            }
            if (ci == 0) {
                int k = (int)(unsigned)(best & 0xffffffffu);
                sidx[cpx] = k;
                idx_out[p0 + cpx] = (float)k;
            }
        }
    }
    __syncthreads();

    // ---- gather + loss (128B-segment stores)
    int px2 = t & 31, cy = t >> 5;
    int kk = sidx[px2];
    const float* er = emb + (size_t)kk * DDIM;
    float* ob = out + (size_t)b * 262144 + hh2 * 32;
    float local = 0.f;
#pragma unroll 4
    for (int it = 0; it < 32; ++it) {
        int c = it * 8 + cy;
        float q = er[c];
        float d = q - ztile[px2][c];
        ob[(size_t)c * 1024 + px2] = q;
        local += d * d;
    }
#pragma unroll
    for (int off = 32; off >= 1; off >>= 1) local += __shfl_down(local, off, 64);
    __shared__ float wsum[4];
    if ((t & 63) == 0) wsum[t >> 6] = local;
    __syncthreads();
    if (t == 0) {
        double s = (double)wsum[0] + (double)wsum[1]
                 + (double)wsum[2] + (double)wsum[3];
        atomicAdd(lossAcc, s);
        __threadfence();
        unsigned old = atomicAdd(doneCnt, 1u);
        if (old == 511u) {
            double tot = atomicAdd(lossAcc, 0.0);
            *loss_out = (float)(tot * (1.25 / 4194304.0));
        }
    }
}

// ----------------------------------------------------------------
extern "C" void kernel_launch(void* const* d_in, const int* in_sizes, int n_in,
                              void* d_out, int out_size, void* d_ws, size_t ws_size,
                              hipStream_t stream) {
    const float* z   = (const float*)d_in[0];
    const float* emb = (const float*)d_in[1];
    float* out = (float*)d_out;
    char* ws = (char*)d_ws;

    unsigned char* Af8 = (unsigned char*)(ws + WS_A8);
    unsigned char* Ef8 = (unsigned char*)(ws + WS_E8);
    unsigned int* keys = (unsigned int*)(ws + WS_KEYS);
    float* zsq      = (float*)(ws + WS_ZSQ);
    float* esq      = (float*)(ws + WS_ESQ);
    double* lossAcc = (double*)(ws + WS_LOSS);
    unsigned* doneCnt = (unsigned*)(ws + WS_CNT);

    prep_kernel<<<768, 256, 0, stream>>>(z, emb, Af8, Ef8, zsq, esq,
                                         lossAcc, doneCnt);
    mfma_score_kernel<<<dim3(16, 128), 256, 0, stream>>>(Af8, Ef8, keys);
    final_kernel<<<512, 256, 0, stream>>>(keys, z, emb, zsq, esq,
                                          out, out + 4194305, out + 4194304,
                                          lossAcc, doneCnt);
}

// Round 13
// 164.218 us; speedup vs baseline: 1.2081x; 1.0367x over previous
//
#include <hip/hip_runtime.h>
#include <cstdint>
#include <cstddef>

#define N_PIX   16384
#define K_EMB   8192
#define DDIM    256

// ws layout (bytes)
// Af8: [mb=128][kk=4][r=128][64B]  (row r of pixel tile, k-range kk*64..+64)
// Ef8: same geometry, but 16B slots XOR-swizzled: slot s stored at s^((r>>1)&3)
#define WS_A8       0           // 4194304
#define WS_E8       4194304     // 2097152
#define WS_KEYS     6291456     // keys [32 pools][16384] uint2   4194304
#define WS_ZSQ      23068672    // 16384*4
#define WS_ESQ      23134208    // 8192*4
#define WS_LOSS     23166976    // 8
#define WS_CNT      23166984    // 4

typedef float f32x16 __attribute__((ext_vector_type(16)));
typedef int   i32x4  __attribute__((ext_vector_type(4)));
typedef int   i32x8  __attribute__((ext_vector_type(8)));

__device__ __forceinline__ unsigned int f32_sortable(float f) {
    unsigned int u = __float_as_uint(f);
    return (u & 0x80000000u) ? ~u : (u | 0x80000000u);
}

// fp32 -> OCP e4m3fn RNE (fallback path; handles subnormals)
__device__ __forceinline__ unsigned char f2fp8(float x) {
    unsigned ub = __float_as_uint(x);
    unsigned sgn = (ub >> 24) & 0x80u;
    unsigned b = ub & 0x7FFFFFFFu;
    unsigned out;
    if (__uint_as_float(b) < 0.015625f) {
        out = (unsigned)(int)rintf(__uint_as_float(b) * 512.0f);
    } else {
        unsigned r = b + 0x7FFFFu + ((b >> 20) & 1u);
        int er = (int)(r >> 23) - 127;
        out = (unsigned)(((er + 7) << 3) | ((r >> 20) & 7u));
    }
    return (unsigned char)(out | sgn);
}

#if defined(__has_builtin)
#if __has_builtin(__builtin_amdgcn_cvt_pk_fp8_f32)
#define HAVE_CVT_FP8 1
#endif
#if __has_builtin(__builtin_amdgcn_fmed3f)
#define HAVE_FMED3 1
#endif
#endif

__device__ __forceinline__ unsigned pack4_fp8(float a, float b, float c, float d) {
#ifdef HAVE_CVT_FP8
    int pk = 0;
    pk = __builtin_amdgcn_cvt_pk_fp8_f32(a, b, pk, false);
    pk = __builtin_amdgcn_cvt_pk_fp8_f32(c, d, pk, true);
    return (unsigned)pk;
#else
    return (unsigned)f2fp8(a) | ((unsigned)f2fp8(b) << 8)
         | ((unsigned)f2fp8(c) << 16) | ((unsigned)f2fp8(d) << 24);
#endif
}

__device__ __forceinline__ void async16(const unsigned char* g, unsigned char* l) {
    __builtin_amdgcn_global_load_lds(
        (const __attribute__((address_space(1))) void*)g,
        (__attribute__((address_space(3))) void*)l, 16, 0, 0);
}

// ---------------------------------------------------------------- kernel 1
// unchanged from R12 (wave-parallel sq, bit-identical np-pairwise order)
__global__ __launch_bounds__(256) void prep_kernel(
        const float* __restrict__ z, const float* __restrict__ emb,
        unsigned char* __restrict__ Af8, unsigned char* __restrict__ Ef8,
        float* __restrict__ zsq, float* __restrict__ esq,
        double* __restrict__ lossAcc, unsigned* __restrict__ doneCnt) {
    __shared__ float tile[32][257];
    __shared__ float sqs[32][17];
    int blk = blockIdx.x;
    int t   = threadIdx.x;
    if (blk < 512) {
        int b   = blk >> 5;
        int hw0 = (blk & 31) * 32;
        const float* zb = z + (size_t)b * 262144 + hw0;
        int c0  = t >> 3;
        int px4 = t & 7;
#pragma unroll
        for (int cc = 0; cc < 8; ++cc) {
            int c = cc * 32 + c0;
            float4 v = *(const float4*)&zb[(size_t)c * 1024 + px4 * 4];
            tile[px4 * 4 + 0][c] = v.x;
            tile[px4 * 4 + 1][c] = v.y;
            tile[px4 * 4 + 2][c] = v.z;
            tile[px4 * 4 + 3][c] = v.w;
        }
        __syncthreads();
        int p0 = b * 1024 + hw0;
        int wv = t >> 6, lane = t & 63;
#pragma unroll
        for (int iter = 0; iter < 8; ++iter) {
            int pl = iter * 4 + wv;
            unsigned pk = pack4_fp8(tile[pl][lane * 4 + 0], tile[pl][lane * 4 + 1],
                                    tile[pl][lane * 4 + 2], tile[pl][lane * 4 + 3]);
            int p  = p0 + pl;
            int mbb = p >> 7, r = p & 127;
            int c = lane * 4;
            *(unsigned*)(Af8 + (size_t)mbb * 32768
                         + (c >> 6) * 8192 + r * 64 + (c & 63)) = pk;
        }
        {
            int row = t >> 3, s0 = t & 7;
            const float* rp = tile[row];
            float a0 = 0.f, a1 = 0.f;
#pragma unroll
            for (int i = 0; i < 16; ++i) {
                float x0 = rp[s0 + 8 * i];
                a0 = __fadd_rn(a0, __fmul_rn(x0, x0));
            }
#pragma unroll
            for (int i = 0; i < 16; ++i) {
                float x1 = rp[128 + s0 + 8 * i];
                a1 = __fadd_rn(a1, __fmul_rn(x1, x1));
            }
            sqs[row][s0]     = a0;
            sqs[row][s0 + 8] = a1;
        }
        __syncthreads();
        if (t < 32) {
            const float* r = sqs[t];
            float h0 = __fadd_rn(
                __fadd_rn(__fadd_rn(r[0], r[1]), __fadd_rn(r[2], r[3])),
                __fadd_rn(__fadd_rn(r[4], r[5]), __fadd_rn(r[6], r[7])));
            float h1 = __fadd_rn(
                __fadd_rn(__fadd_rn(r[8], r[9]), __fadd_rn(r[10], r[11])),
                __fadd_rn(__fadd_rn(r[12], r[13]), __fadd_rn(r[14], r[15])));
            zsq[p0 + t] = __fadd_rn(h0, h1);
        }
        if (blk == 0 && t == 0) { *lossAcc = 0.0; *doneCnt = 0u; }
    } else {
        int k0 = (blk - 512) * 32;
        const float4* eg = (const float4*)(emb + (size_t)k0 * DDIM);
#pragma unroll
        for (int i = 0; i < 8; ++i) {
            int idx = i * 256 + t;
            int row = idx >> 6, c4 = idx & 63;
            float4 v = eg[idx];
            *(float4*)&tile[row][c4 * 4] = v;
        }
        __syncthreads();
#pragma unroll
        for (int i = 0; i < 8; ++i) {
            int idx = i * 256 + t;
            int row = idx >> 6, c4 = idx & 63;
            const float* rp = &tile[row][c4 * 4];
            int kg = k0 + row;
            int nbb = kg >> 7, rr = kg & 127;
            int c  = c4 * 4;
            int kk = c >> 6, kl = c & 63;
            int s  = kl >> 4;
            int pos = kk * 8192 + rr * 64
                    + ((s ^ ((rr >> 1) & 3)) << 4) + (kl & 15);
            *(unsigned*)(Ef8 + (size_t)nbb * 32768 + pos) =
                pack4_fp8(rp[0] * 8192.0f, rp[1] * 8192.0f,
                          rp[2] * 8192.0f, rp[3] * 8192.0f);
        }
        {
            int row = t >> 3, s0 = t & 7;
            const float* rp = tile[row];
            float a0 = 0.f, a1 = 0.f;
#pragma unroll
            for (int i = 0; i < 16; ++i) {
                float x0 = rp[s0 + 8 * i];
                a0 = __fadd_rn(a0, __fmul_rn(x0, x0));
            }
#pragma unroll
            for (int i = 0; i < 16; ++i) {
                float x1 = rp[128 + s0 + 8 * i];
                a1 = __fadd_rn(a1, __fmul_rn(x1, x1));
            }
            sqs[row][s0]     = a0;
            sqs[row][s0 + 8] = a1;
        }
        __syncthreads();
        if (t < 32) {
            const float* r = sqs[t];
            float h0 = __fadd_rn(
                __fadd_rn(__fadd_rn(r[0], r[1]), __fadd_rn(r[2], r[3])),
                __fadd_rn(__fadd_rn(r[4], r[5]), __fadd_rn(r[6], r[7])));
            float h1 = __fadd_rn(
                __fadd_rn(__fadd_rn(r[8], r[9]), __fadd_rn(r[10], r[11])),
                __fadd_rn(__fadd_rn(r[12], r[13]), __fadd_rn(r[14], r[15])));
            esq[k0 + t] = __fadd_rn(h0, h1);
        }
    }
}

// winner float (idx in low 13 mantissa bits) -> integer key
__device__ __forceinline__ unsigned pack_key(float w) {
    float uf = __builtin_fmaf(w, -512.0f, 262144.0f);
    uf = fminf(uf, 524287.0f);
    unsigned u = (unsigned)uf;
    return (u << 13) | (__float_as_uint(w) & 0x1FFFu);
}

// ---------------------------------------------------------------- kernel 2
// R13: register-pressure fix. Wave tile 32 rows x 128 cols (was 64x64):
// afr[4] (32 regs, was 64), t2a/t2b[16] (32, was 64), ONE f32x16 acc live
// (ct processed sequentially; 16 regs, was 64). Live state ~90 regs ->
// fits VGPR file; kills the v_accvgpr_read/write shuttle that inflated
// VALUBusy to 52%. Same MFMA count; epilogue simplifies (no shfl merge;
// pool = lane<16 half). ep-reduce + keys format + final unchanged.
__global__ __launch_bounds__(256) void mfma_score_kernel(
        const unsigned char* __restrict__ Af8,
        const unsigned char* __restrict__ Ef8,
        unsigned int* __restrict__ keys) {
    union __align__(16) SM {
        unsigned char Bs[2][32768];      // 64 KB: E tiles (all K), dbuf
        struct { uint2 ep[128][33]; } e; // 33.8 KB, reused in epilogue
    };
    __shared__ SM sm;

    const int g  = blockIdx.x;      // 0..15
    const int mb = blockIdx.y;      // 0..127
    const int t = threadIdx.x;
    const int w = t >> 6, lane = t & 63;
    const int l31 = lane & 31, h = lane >> 5;

    // stage first E tile into Bs[0]
    {
        const unsigned char* Eg = Ef8 + (size_t)(g * 4) * 32768 + t * 16;
#pragma unroll
        for (int ch = 0; ch < 8; ++ch)
            async16(Eg + ch * 4096, &sm.Bs[0][ch * 4096 + t * 16]);
    }

    // A-fragments: wave w owns rows w*32..w*32+32; lane row = w*32+l31
    i32x8 afr[4];
    {
        const unsigned char* Ab = Af8 + (size_t)mb * 32768;
        int r = w * 32 + l31;
#pragma unroll
        for (int kk = 0; kk < 4; ++kk) {
            const unsigned char* p = Ab + kk * 8192 + r * 64 + h * 32;
            i32x4 lo = *(const i32x4*)p;
            i32x4 hi = *(const i32x4*)(p + 16);
            afr[kk] = __builtin_shufflevector(lo, hi, 0, 1, 2, 3, 4, 5, 6, 7);
        }
    }

    const float NEGINF = __int_as_float(0xFF800000);
    float t2a[16], t2b[16];
#pragma unroll
    for (int q = 0; q < 16; ++q) { t2a[q] = NEGINF; t2b[q] = NEGINF; }

    __syncthreads();   // E0 staged

#pragma unroll 1
    for (int j = 0; j < 4; ++j) {
        const int cur = j & 1, nxt = cur ^ 1;

        // issue next-tile stage batch first (in flight during MFMAs)
        if (j < 3) {
            const unsigned char* Eg =
                Ef8 + (size_t)(g * 4 + j + 1) * 32768 + t * 16;
#pragma unroll
            for (int ch = 0; ch < 8; ++ch)
                async16(Eg + ch * 4096, &sm.Bs[nxt][ch * 4096 + t * 16]);
        }

        const int nb = g * 4 + j;
#pragma unroll
        for (int ct = 0; ct < 4; ++ct) {
            f32x16 acc;
#pragma unroll
            for (int q = 0; q < 16; ++q) acc[q] = 0.f;

            const int c  = ct * 32 + l31;      // emb col in tile
            const int m  = (c >> 1) & 3;       // slot swizzle
            const int s0 = h * 2;
            __builtin_amdgcn_s_setprio(1);
#pragma unroll
            for (int kk = 0; kk < 4; ++kk) {
                int base = kk * 8192 + c * 64;
                i32x4 lo = *(const i32x4*)
                    &sm.Bs[cur][base + ((s0 ^ m) << 4)];
                i32x4 hi = *(const i32x4*)
                    &sm.Bs[cur][base + (((s0 + 1) ^ m) << 4)];
                i32x8 bf = __builtin_shufflevector(lo, hi,
                                                   0, 1, 2, 3, 4, 5, 6, 7);
                acc = __builtin_amdgcn_mfma_scale_f32_32x32x64_f8f6f4(
                        afr[kk], bf, acc,
                        0, 0,                 // fp8 / fp8
                        0, 0x7F7F7F7F,        // scale A = 1.0
                        0, 0x7F7F7F7F);       // scale B = 1.0
            }
            __builtin_amdgcn_s_setprio(0);

            const unsigned idxc = (unsigned)(nb * 128 + c);
#pragma unroll
            for (int q = 0; q < 16; ++q) {
                float v = acc[q];
                float wv = __uint_as_float(
                    (__float_as_uint(v) & 0xFFFFE000u) | idxc);
                float a0 = t2a[q], b0 = t2b[q];
#ifdef HAVE_FMED3
                float bn = __builtin_amdgcn_fmed3f(a0, wv, b0);
                t2a[q] = fmaxf(a0, wv);
                t2b[q] = bn;
#else
                float mn = fminf(a0, wv);
                t2a[q] = fmaxf(a0, wv);
                t2b[q] = fmaxf(b0, mn);
#endif
            }
        }
        __syncthreads();   // drains stage batch; syncs buffers
    }

    // epilogue: lane writes its 16 (row, col-slot) top-2 pairs directly.
    // C/D layout: col = lane&31, row = (q&3) + 8*(q>>2) + 4*h.
#pragma unroll
    for (int q = 0; q < 16; ++q) {
        int row = w * 32 + (q & 3) + 8 * (q >> 2) + 4 * h;
        sm.e.ep[row][l31] = make_uint2(pack_key(t2a[q]), pack_key(t2b[q]));
    }
    __syncthreads();

    {
        int row = t >> 1, half = t & 1, h0 = half * 16;
        uint2 mv = sm.e.ep[row][h0];
#pragma unroll
        for (int i = 1; i < 16; ++i) {
            uint2 av = sm.e.ep[row][h0 + i];
            unsigned n0 = min(mv.x, av.x);
            unsigned n1 = min(max(mv.x, av.x), min(mv.y, av.y));
            mv.x = n0; mv.y = n1;
        }
        ((uint2*)keys)[(size_t)(g * 2 + half) * N_PIX + (mb * 128 + row)] = mv;
    }
}

// ---------------------------------------------------------------- kernel 3
// unchanged from R12 (32-px blocks, parallel rescore)
__global__ __launch_bounds__(256) void final_kernel(
        const unsigned int* __restrict__ keys,
        const float* __restrict__ z, const float* __restrict__ emb,
        const float* __restrict__ zsq, const float* __restrict__ esq,
        float* __restrict__ out, float* __restrict__ idx_out,
        float* __restrict__ loss_out,
        double* __restrict__ lossAcc, unsigned* __restrict__ doneCnt) {
    __shared__ float ztile[32][257];
    __shared__ uint2 kt[32][33];
    __shared__ unsigned short scand[32][64];
    __shared__ unsigned long long ckey[2048];
    __shared__ int   soff[33];
    __shared__ int   scnt[32];
    __shared__ unsigned char pxmap[2048];
    __shared__ float szs[32];
    __shared__ int   sidx[32];

    int blk = blockIdx.x;                // 0..511 = b*32 + hh2
    int b = blk >> 5, hh2 = blk & 31;
    int t = threadIdx.x;
    int p0 = b * 1024 + hh2 * 32;
    const float* zb = z + (size_t)b * 262144 + hh2 * 32;
    {
        int c0 = t >> 3, px4 = t & 7;
#pragma unroll
        for (int cc = 0; cc < 8; ++cc) {
            int c = cc * 32 + c0;
            float4 v = *(const float4*)&zb[(size_t)c * 1024 + px4 * 4];
            ztile[px4 * 4 + 0][c] = v.x;
            ztile[px4 * 4 + 1][c] = v.y;
            ztile[px4 * 4 + 2][c] = v.z;
            ztile[px4 * 4 + 3][c] = v.w;
        }
    }
    {
        const uint2* kg = (const uint2*)keys;
#pragma unroll
        for (int itr = 0; itr < 4; ++itr) {
            int idx = itr * 256 + t;
            int px = idx & 31, hf = idx >> 5;
            kt[px][hf] = kg[(size_t)hf * N_PIX + p0 + px];
        }
    }
    if (t < 32) szs[t] = zsq[p0 + t];
    __syncthreads();

    // ---- Phase A: threshold + compact candidate lists (4 waves x 8 px)
    {
        int wq = t >> 6, lane = t & 63;
#pragma unroll 1
        for (int i = 0; i < 8; ++i) {
            int px = wq * 8 + i;
            uint2 ka = (lane < 32) ? kt[px][lane] : make_uint2(~0u, ~0u);
            unsigned m = min(ka.x, ka.y);
#pragma unroll
            for (int off = 32; off >= 1; off >>= 1)
                m = min(m, (unsigned)__shfl_xor((int)m, off, 64));
            unsigned thr = (m >> 13) + 1600;   // margin 1600*2^-21 = 7.6e-4

            bool h0 = (lane < 32) && ((ka.x >> 13) <= thr);
            bool h1 = (lane < 32) && ((ka.y >> 13) <= thr);
            unsigned long long m0 = __ballot(h0);
            unsigned long long m1 = __ballot(h1);
            int c0 = __popcll(m0);
            unsigned long long below = (lane == 63) ? ~0ull >> 1
                                     : ((1ull << lane) - 1);
            if (h0) scand[px][__popcll(m0 & below)] =
                (unsigned short)(ka.x & 0x1FFFu);
            if (h1) scand[px][c0 + __popcll(m1 & below)] =
                (unsigned short)(ka.y & 0x1FFFu);
            if (lane == 0) scnt[px] = c0 + __popcll(m1);
        }
    }
    __syncthreads();

    // ---- scan 32 counts -> soff (wave 0), then pxmap
    if (t < 64) {
        int v = (t < 32) ? scnt[t] : 0;
#pragma unroll
        for (int o = 1; o < 32; o <<= 1) {
            int u = __shfl_up(v, o, 64);
            if (t >= o) v += u;
        }
        if (t < 32) soff[t + 1] = v;
        if (t == 0) soff[0] = 0;
    }
    __syncthreads();
    int total = soff[32];
    for (int f = t; f < total; f += 256) {
        int lo = 0, hi = 31;
        while (lo < hi) {
            int mid = (lo + hi + 1) >> 1;
            if (soff[mid] <= f) lo = mid; else hi = mid - 1;
        }
        pxmap[f] = (unsigned char)lo;
    }
    __syncthreads();

    // ---- Phase B: parallel rescore, one candidate per 16-lane group
    {
        int gid = t >> 4, l16 = t & 15;
        const float4* emb4 = (const float4*)emb;
#pragma unroll 1
        for (int f = gid; f < total; f += 16) {
            int px = pxmap[f];
            int k  = scand[px][f - soff[px]];
            double d = 0.0;
#pragma unroll
            for (int q = 0; q < 4; ++q) {
                float4 ev = emb4[(size_t)k * 64 + q * 16 + l16];
                const float* zp = &ztile[px][(q * 16 + l16) * 4];
                d += (double)zp[0] * ev.x + (double)zp[1] * ev.y
                   + (double)zp[2] * ev.z + (double)zp[3] * ev.w;
            }
#pragma unroll
            for (int o = 1; o < 16; o <<= 1) d += __shfl_xor(d, o, 64);
            if (l16 == 0) {
                float df = (float)d;
                float s  = __fsub_rn(__fadd_rn(szs[px], esq[k]),
                                     __fmul_rn(2.0f, df));
                ckey[f] = ((unsigned long long)f32_sortable(s) << 32)
                        | (unsigned)k;
            }
        }
    }
    __syncthreads();

    // ---- Phase C: per-pixel u64 min (16 threads each, 2 passes)
    {
        int ci = t & 15;
#pragma unroll
        for (int pass = 0; pass < 2; ++pass) {
            int cpx = (t >> 4) + pass * 16;
            unsigned long long best = ~0ull;
            for (int f = soff[cpx] + ci; f < soff[cpx + 1]; f += 16) {
                unsigned long long v = ckey[f];
                best = v < best ? v : best;
            }
#pragma unroll
            for (int o = 1; o < 16; o <<= 1) {
                unsigned long long ov =
                    (unsigned long long)__shfl_xor((long long)best, o, 64);
                best = ov < best ? ov : best;
            }
            if (ci == 0) {
                int k = (int)(unsigned)(best & 0xffffffffu);
                sidx[cpx] = k;
                idx_out[p0 + cpx] = (float)k;
            }
        }
    }
    __syncthreads();

    // ---- gather + loss (128B-segment stores)
    int px2 = t & 31, cy = t >> 5;
    int kk = sidx[px2];
    const float* er = emb + (size_t)kk * DDIM;
    float* ob = out + (size_t)b * 262144 + hh2 * 32;
    float local = 0.f;
#pragma unroll 4
    for (int it = 0; it < 32; ++it) {
        int c = it * 8 + cy;
        float q = er[c];
        float d = q - ztile[px2][c];
        ob[(size_t)c * 1024 + px2] = q;
        local += d * d;
    }
#pragma unroll
    for (int off = 32; off >= 1; off >>= 1) local += __shfl_down(local, off, 64);
    __shared__ float wsum[4];
    if ((t & 63) == 0) wsum[t >> 6] = local;
    __syncthreads();
    if (t == 0) {
        double s = (double)wsum[0] + (double)wsum[1]
                 + (double)wsum[2] + (double)wsum[3];
        atomicAdd(lossAcc, s);
        __threadfence();
        unsigned old = atomicAdd(doneCnt, 1u);
        if (old == 511u) {
            double tot = atomicAdd(lossAcc, 0.0);
            *loss_out = (float)(tot * (1.25 / 4194304.0));
        }
    }
}

// ----------------------------------------------------------------
extern "C" void kernel_launch(void* const* d_in, const int* in_sizes, int n_in,
                              void* d_out, int out_size, void* d_ws, size_t ws_size,
                              hipStream_t stream) {
    const float* z   = (const float*)d_in[0];
    const float* emb = (const float*)d_in[1];
    float* out = (float*)d_out;
    char* ws = (char*)d_ws;

    unsigned char* Af8 = (unsigned char*)(ws + WS_A8);
    unsigned char* Ef8 = (unsigned char*)(ws + WS_E8);
    unsigned int* keys = (unsigned int*)(ws + WS_KEYS);
    float* zsq      = (float*)(ws + WS_ZSQ);
    float* esq      = (float*)(ws + WS_ESQ);
    double* lossAcc = (double*)(ws + WS_LOSS);
    unsigned* doneCnt = (unsigned*)(ws + WS_CNT);

    prep_kernel<<<768, 256, 0, stream>>>(z, emb, Af8, Ef8, zsq, esq,
                                         lossAcc, doneCnt);
    mfma_score_kernel<<<dim3(16, 128), 256, 0, stream>>>(Af8, Ef8, keys);
    final_kernel<<<512, 256, 0, stream>>>(keys, z, emb, zsq, esq,
                                          out, out + 4194305, out + 4194304,
                                          lossAcc, doneCnt);
}